// Round 8
// baseline (390.880 us; speedup 1.0000x reference)
//
#include <hip/hip_runtime.h>
#include <hip/hip_bf16.h>
#include <math.h>

typedef unsigned short u16;
typedef unsigned int u32;
typedef unsigned long long u64;
typedef signed char i8;

constexpr int NB = 64, NS = 128, NDM = 1024, NH = 16, NDK = 64;
constexpr int NM = NB * NS;  // 8192
constexpr float QEPS = 1e-8f;

typedef __attribute__((ext_vector_type(8))) short short8;
typedef __attribute__((ext_vector_type(4))) float f32x4;
typedef __attribute__((ext_vector_type(4))) int i32x4;

__device__ __forceinline__ u32 fenc(float f) {
  u32 u = __float_as_uint(f);
  return (u & 0x80000000u) ? ~u : (u | 0x80000000u);
}
__device__ __forceinline__ float fdec(u32 u) {
  u = (u & 0x80000000u) ? (u & 0x7FFFFFFFu) : ~u;
  return __uint_as_float(u);
}
// quantized values are small integers -> exact bf16 truncation
__device__ __forceinline__ u16 f2bf(float f) { return (u16)(__float_as_uint(f) >> 16); }
__device__ __forceinline__ float bf2f(u16 u) { return __uint_as_float(((u32)u) << 16); }

// async global->LDS, 16B per lane; lds dest = wave-uniform base + lane*16
__device__ __forceinline__ void glds16(const void* g, void* l) {
  __builtin_amdgcn_global_load_lds(
      (const __attribute__((address_space(1))) void*)(unsigned long long)(uintptr_t)g,
      (__attribute__((address_space(3))) void*)(u32)(uintptr_t)l, 16, 0, 0);
}

// ---- scale slots (u32/float at ws offset 0) ----
// [0..2] enc max(q,k,v)  [3..6] enc absmax(W*)  [7] enc max(x)
// [8..135] absmax_q per s; [136..263] absmax_k; [264..391] absmax_v (plain float bits)
// [392..519] colmax_p per j (plain float bits)

// mask[B,S,S] int32 -> bitmask [B*S][2] u64; block 0 also zeroes the scale slots
__global__ void maskbits_kernel(const int* __restrict__ mask, u64* __restrict__ mb,
                                u32* __restrict__ scl) {
  if (blockIdx.x == 0) {
    for (int i = threadIdx.x; i < 2048; i += blockDim.x) scl[i] = 0u;
  }
  int row = blockIdx.x * 4 + (threadIdx.x >> 6);
  int lane = threadIdx.x & 63;
  const int* mrow = mask + (size_t)row * NS;
  u64 b0 = __ballot(mrow[lane] != 0);
  u64 b1 = __ballot(mrow[64 + lane] != 0);
  if (lane == 0) { mb[row * 2] = b0; mb[row * 2 + 1] = b1; }
}

// fused 7-way max reduce: y=0..2 max(q,k,v); y=3..6 absmax(Wq..Wo)
__global__ void fused_max_kernel(const float* __restrict__ q, const float* __restrict__ k,
                                 const float* __restrict__ v, const float* __restrict__ w0,
                                 const float* __restrict__ w1, const float* __restrict__ w2,
                                 const float* __restrict__ w3, u32* __restrict__ sclu) {
  int y = blockIdx.y;
  const float* src; size_t n4; int ab;
  switch (y) {
    case 0: src = q; n4 = (size_t)NM * NDM / 4; ab = 0; break;
    case 1: src = k; n4 = (size_t)NM * NDM / 4; ab = 0; break;
    case 2: src = v; n4 = (size_t)NM * NDM / 4; ab = 0; break;
    case 3: src = w0; n4 = (size_t)NDM * NDM / 4; ab = 1; break;
    case 4: src = w1; n4 = (size_t)NDM * NDM / 4; ab = 1; break;
    case 5: src = w2; n4 = (size_t)NDM * NDM / 4; ab = 1; break;
    default: src = w3; n4 = (size_t)NDM * NDM / 4; ab = 1; break;
  }
  float m = -INFINITY;
  size_t stride = (size_t)gridDim.x * blockDim.x;
  for (size_t i = (size_t)blockIdx.x * blockDim.x + threadIdx.x; i < n4; i += stride) {
    float4 f = ((const float4*)src)[i];
    if (ab) { f.x = fabsf(f.x); f.y = fabsf(f.y); f.z = fabsf(f.z); f.w = fabsf(f.w); }
    m = fmaxf(m, fmaxf(fmaxf(f.x, f.y), fmaxf(f.z, f.w)));
  }
  for (int off = 32; off; off >>= 1) m = fmaxf(m, __shfl_down(m, off));
  __shared__ float sm[4];
  if ((threadIdx.x & 63) == 0) sm[threadIdx.x >> 6] = m;
  __syncthreads();
  if (threadIdx.x == 0) {
    float r = fmaxf(fmaxf(sm[0], sm[1]), fmaxf(sm[2], sm[3]));
    atomicMax(&sclu[y], fenc(r));
  }
}

// weight quant -> i8 (-127..127) + per-output-channel column sums (for u8 shift fix)
__global__ __launch_bounds__(256)
void quant_w_i8_kernel(const float* __restrict__ w0, const float* __restrict__ w1,
                       const float* __restrict__ w2, const float* __restrict__ w3,
                       i8* __restrict__ dst, int* __restrict__ colsum,
                       const u32* __restrict__ sclu) {
  int y = blockIdx.y, row = blockIdx.x, tid = threadIdx.x;
  const float* src = (y == 0 ? w0 : y == 1 ? w1 : y == 2 ? w2 : w3) + (size_t)row * NDM;
  float s = fmaxf(fdec(sclu[3 + y]), QEPS) / 127.0f;
  float4 f = ((const float4*)src)[tid];
  int a = (int)fminf(fmaxf(rintf(f.x / s), -127.f), 127.f);
  int b = (int)fminf(fmaxf(rintf(f.y / s), -127.f), 127.f);
  int c = (int)fminf(fmaxf(rintf(f.z / s), -127.f), 127.f);
  int d = (int)fminf(fmaxf(rintf(f.w / s), -127.f), 127.f);
  ((int*)(dst + (size_t)y * NDM * NDM + (size_t)row * NDM))[tid] =
      (a & 255) | ((b & 255) << 8) | ((c & 255) << 16) | ((d & 255) << 24);
  int ssum = a + b + c + d;
  for (int off = 32; off; off >>= 1) ssum += __shfl_down(ssum, off);
  __shared__ int sm[4];
  if ((tid & 63) == 0) sm[tid >> 6] = ssum;
  __syncthreads();
  if (tid == 0) colsum[y * NDM + row] = sm[0] + sm[1] + sm[2] + sm[3];
}

// uint8 activation fake-quant -> shifted i8 (q-128); y selects source/slot/dst
__global__ void quant_a_kernel(const float* __restrict__ s0, const float* __restrict__ s1,
                               const float* __restrict__ s2, i8* __restrict__ dst,
                               const u32* __restrict__ sclu, int slot_base) {
  int y = blockIdx.y;
  const float* src = y == 0 ? s0 : y == 1 ? s1 : s2;
  i8* d = dst + (size_t)y * NM * NDM;
  float s = fmaxf(fdec(sclu[slot_base + y]), QEPS) / 255.0f;
  size_t n4 = (size_t)NM * NDM / 4;
  size_t stride = (size_t)gridDim.x * blockDim.x;
  for (size_t i = (size_t)blockIdx.x * blockDim.x + threadIdx.x; i < n4; i += stride) {
    float4 f = ((const float4*)src)[i];
    int a = (int)fminf(fmaxf(rintf(f.x / s), 0.f), 255.f) - 128;
    int b = (int)fminf(fmaxf(rintf(f.y / s), 0.f), 255.f) - 128;
    int c = (int)fminf(fmaxf(rintf(f.z / s), 0.f), 255.f) - 128;
    int e = (int)fminf(fmaxf(rintf(f.w / s), 0.f), 255.f) - 128;
    ((int*)d)[i] = (a & 255) | ((b & 255) << 8) | ((c & 255) << 16) | ((e & 255) << 24);
  }
}

// proj fp32 -> int8 with per-s scale; y=0..2 selects q/k/v
__global__ void qkv_i8_kernel(const float* __restrict__ projbase, i8* __restrict__ dstbase,
                              const float* __restrict__ scl) {
  int y = blockIdx.y;
  const float* src = projbase + (size_t)y * NM * NDM;
  i8* dst = dstbase + (size_t)y * NM * NDM;
  const float* sb = scl + 8 + y * 128;
  size_t n4 = (size_t)NM * NDM / 4;
  size_t stride = (size_t)gridDim.x * blockDim.x;
  for (size_t i = (size_t)blockIdx.x * blockDim.x + threadIdx.x; i < n4; i += stride) {
    int s_idx = (int)((i >> 8) & 127);
    float s = fmaxf(sb[s_idx], QEPS) / 127.0f;
    float4 f = ((const float4*)src)[i];
    int a = (int)fminf(fmaxf(rintf(f.x / s), -128.f), 127.f);
    int b = (int)fminf(fmaxf(rintf(f.y / s), -128.f), 127.f);
    int c = (int)fminf(fmaxf(rintf(f.z / s), -128.f), 127.f);
    int d = (int)fminf(fmaxf(rintf(f.w / s), -128.f), 127.f);
    ((int*)dst)[i] = (a & 255) | ((b & 255) << 8) | ((c & 255) << 16) | ((d & 255) << 24);
  }
}

// ---------------- GEMM: i8 MFMA, dbuf glds16, 64x32 wave tile ----------------
// BM=128 BN=64: acc[4][2]=32 AGPR + frags ~24 VGPR -> under the 128-reg bucket
// (old 4x4 acc = 64 AGPR + 76 VGPR = ~140 -> 2 waves/SIMD cliff, m69).
constexpr int BM = 128, BN = 64, BK = 64, KTILES = NDM / BK;

template <bool PROJ>
__global__ __launch_bounds__(256, 4)
void gemm_kernel(const i8* __restrict__ Abase, const i8* __restrict__ Wbase,
                 const int* __restrict__ colsum, const float* __restrict__ b0,
                 const float* __restrict__ b1, const float* __restrict__ b2,
                 float* __restrict__ Cbase, u32* __restrict__ sclu,
                 float* __restrict__ rmax_part) {
  constexpr int K = NDM, N = NDM;
  const int z = PROJ ? blockIdx.z : 0;
  const i8* A = Abase + (size_t)z * NM * NDM;
  const i8* Wt = PROJ ? (Wbase + (size_t)z * NDM * NDM) : Wbase;
  const float* bias = PROJ ? (z == 0 ? b0 : z == 1 ? b1 : b2) : b0;
  float* C = PROJ ? (Cbase + (size_t)z * NM * NDM) : Cbase;
  const u32* slot_in = PROJ ? (sclu + z) : (sclu + 7);
  const u32* slot_w = PROJ ? (sclu + 3 + z) : (sclu + 6);
  const int* cs = colsum + (PROJ ? z : 3) * NDM;

  __shared__ __align__(16) i8 As[2][BM][BK];  // 16 KB (dbuf)
  __shared__ __align__(16) i8 Bs[2][BN][BK];  // 8 KB (dbuf)
  __shared__ float rmax2[4][64];

  const int tid = threadIdx.x;
  const int lane = tid & 63, wave = tid >> 6;
  const int wm = (wave & 1) * 64, wn = (wave >> 1) * 32;
  const int r16 = lane & 15, quad = lane >> 4;
  const int bm = blockIdx.x * BM, bn = blockIdx.y * BN;

  const int lrow = lane >> 2, lcol = (lane & 3) * 16;  // 16 rows per glds16, 64B rows
  const i8* Ab = A + (size_t)(bm + wave * 32 + lrow) * K + lcol;
  const i8* Bb = Wt + (size_t)(bn + wave * 16 + lrow) * K + lcol;

  i32x4 acc[4][2] = {};

  // prologue: stage tile 0
  glds16(Ab, &As[0][wave * 32][0]);
  glds16(Ab + (size_t)16 * K, &As[0][wave * 32 + 16][0]);
  glds16(Bb, &Bs[0][wave * 16][0]);
  __syncthreads();

  int cur = 0;
  for (int t = 0; t < KTILES; t++) {
    if (t + 1 < KTILES) {  // issue next tile's loads BEFORE computing current
      int k0 = (t + 1) * BK;
      glds16(Ab + k0, &As[cur ^ 1][wave * 32][0]);
      glds16(Ab + (size_t)16 * K + k0, &As[cur ^ 1][wave * 32 + 16][0]);
      glds16(Bb + k0, &Bs[cur ^ 1][wave * 16][0]);
    }
    i32x4 af[4], bfr[2];
#pragma unroll
    for (int i = 0; i < 4; i++)
      af[i] = *(const i32x4*)(&As[cur][wm + i * 16 + r16][quad * 16]);
#pragma unroll
    for (int j = 0; j < 2; j++)
      bfr[j] = *(const i32x4*)(&Bs[cur][wn + j * 16 + r16][quad * 16]);
#pragma unroll
    for (int i = 0; i < 4; i++)
#pragma unroll
      for (int j = 0; j < 2; j++)
        acc[i][j] = __builtin_amdgcn_mfma_i32_16x16x64_i8(af[i], bfr[j], acc[i][j], 0, 0, 0);
    __syncthreads();  // drains this iter's prefetch (vmcnt0) + fences buffer reuse
    cur ^= 1;
  }

  float s_in = fmaxf(fdec(*slot_in), QEPS) / 255.0f;
  float s_w = fmaxf(fdec(*slot_w), QEPS) / 127.0f;
  float sc = s_in * s_w;

  float bq[2];
  int csj[2];
#pragma unroll
  for (int j = 0; j < 2; j++) {
    int gc = bn + wn + j * 16 + r16;
    bq[j] = rintf(bias[gc] / sc) * sc;
    csj[j] = cs[gc] << 7;  // +128 * colsum(W): undoes the x-128 input shift
  }
#pragma unroll
  for (int i = 0; i < 4; i++) {
#pragma unroll
    for (int r = 0; r < 4; r++) {
      int l64 = i * 16 + quad * 4 + r;  // 0..63 within wave-M group
      int gr = bm + wm + l64;
      float rm = 0.0f;
#pragma unroll
      for (int j = 0; j < 2; j++) {
        int gc = bn + wn + j * 16 + r16;
        float val = (float)(acc[i][j][r] + csj[j]) * sc + bq[j];
        C[(size_t)gr * N + gc] = val;
        if (PROJ) rm = fmaxf(rm, fabsf(val));
      }
      if (PROJ) {
#pragma unroll
        for (int off = 1; off < 16; off <<= 1) rm = fmaxf(rm, __shfl_xor(rm, off));
        if (r16 == 0) rmax2[wave][l64] = rm;
      }
    }
  }
  if (PROJ) {
    // per-block rowmax vector -> scratch (coalesced store; NO atomics)
    __syncthreads();
    if (tid < BM) {
      int g = tid >> 6, l = tid & 63;  // waves {g, g+2} share wm group g
      float m = fmaxf(rmax2[g][l], rmax2[g + 2][l]);
      int blockId = z * 1024 + blockIdx.x * 16 + blockIdx.y;
      rmax_part[(size_t)blockId * 128 + tid] = m;
    }
  }
}

// rmax_part[z*1024 + b][lr] -> scl[8 + z*128 + lr] = max over b (same value set as
// the old atomics; max of nonneg floats is exact/order-free)
__global__ void rmax_reduce_kernel(const float* __restrict__ part, u32* __restrict__ sclu) {
  int slot = blockIdx.x;  // 0..383
  int z = slot >> 7, lr = slot & 127;
  const float* base = part + (size_t)z * 1024 * 128 + lr;
  float m = 0.0f;
  for (int i = threadIdx.x; i < 1024; i += blockDim.x) m = fmaxf(m, base[(size_t)i * 128]);
  for (int off = 32; off; off >>= 1) m = fmaxf(m, __shfl_down(m, off));
  __shared__ float sm[4];
  if ((threadIdx.x & 63) == 0) sm[threadIdx.x >> 6] = m;
  __syncthreads();
  if (threadIdx.x == 0)
    sclu[8 + slot] = __float_as_uint(fmaxf(fmaxf(sm[0], sm[1]), fmaxf(sm[2], sm[3])));
}

// ---------------- attention ----------------
// Phase 1: QK^T + softmax; per-block colmax vector -> scratch (NO atomics; a tiny
// reduce kernel computes the identical per-j max afterwards)
__global__ __launch_bounds__(256)
void attn_colmax_kernel(const i8* __restrict__ qi8, const i8* __restrict__ ki8,
                        const u64* __restrict__ mb, const float* __restrict__ scl,
                        float* __restrict__ cm_part) {
  const int bh = blockIdx.x, b = bh >> 4, h = bh & 15;
  const int tid = threadIdx.x, lane = tid & 63, wave = tid >> 6;
  const int r16 = lane & 15, quad = lane >> 4;

  __shared__ __align__(16) i8 Qs[NS][80];
  __shared__ __align__(16) i8 Ks[NS][80];
  __shared__ float sqv[NS], skv[NS];
  __shared__ float cmw[4][NS];

  {
    int row = tid >> 1, half = (tid & 1) * 32;
    const i8* qp = qi8 + (size_t)(b * NS + row) * NDM + h * NDK + half;
    const i8* kp = ki8 + (size_t)(b * NS + row) * NDM + h * NDK + half;
    *(int4*)&Qs[row][half] = *(const int4*)qp;
    *(int4*)&Qs[row][half + 16] = *(const int4*)(qp + 16);
    *(int4*)&Ks[row][half] = *(const int4*)kp;
    *(int4*)&Ks[row][half + 16] = *(const int4*)(kp + 16);
    if (tid < NS) {
      sqv[tid] = fmaxf(scl[8 + tid], QEPS) / 127.0f;
      skv[tid] = fmaxf(scl[8 + 128 + tid], QEPS) / 127.0f;
    }
  }
  __syncthreads();

  const int rowbase = wave * 32;
  i32x4 acc[2][8] = {};
#pragma unroll
  for (int mt = 0; mt < 2; mt++) {
    i32x4 a = *(const i32x4*)&Qs[rowbase + mt * 16 + r16][quad * 16];
#pragma unroll
    for (int nt = 0; nt < 8; nt++) {
      i32x4 bfrag = *(const i32x4*)&Ks[nt * 16 + r16][quad * 16];
      acc[mt][nt] = __builtin_amdgcn_mfma_i32_16x16x64_i8(a, bfrag, acc[mt][nt], 0, 0, 0);
    }
  }

  float skc[8], cm[8];
#pragma unroll
  for (int nt = 0; nt < 8; nt++) { skc[nt] = skv[nt * 16 + r16]; cm[nt] = 0.0f; }

#pragma unroll
  for (int mt = 0; mt < 2; mt++) {
#pragma unroll
    for (int r = 0; r < 4; r++) {
      int row = rowbase + mt * 16 + quad * 4 + r;
      float sq = sqv[row];
      const u64* mrow = mb + ((size_t)b * NS + row) * 2;
      u64 m0 = mrow[0], m1 = mrow[1];
      float vals[8];
      float mx = -INFINITY;
#pragma unroll
      for (int nt = 0; nt < 8; nt++) {
        float v = (float)acc[mt][nt][r] * (sq * skc[nt]) * 0.125f;
        u64 bits = nt < 4 ? m0 : m1;
        if (((bits >> ((nt * 16 + r16) & 63)) & 1ull) == 0) v = -1e9f;
        vals[nt] = v;
        mx = fmaxf(mx, v);
      }
#pragma unroll
      for (int off = 1; off < 16; off <<= 1) mx = fmaxf(mx, __shfl_xor(mx, off));
      float sum = 0.0f;
#pragma unroll
      for (int nt = 0; nt < 8; nt++) { vals[nt] = __expf(vals[nt] - mx); sum += vals[nt]; }
#pragma unroll
      for (int off = 1; off < 16; off <<= 1) sum += __shfl_xor(sum, off);
#pragma unroll
      for (int nt = 0; nt < 8; nt++) {
        float p = vals[nt] / sum;
        cm[nt] = fmaxf(cm[nt], p);
      }
    }
  }

#pragma unroll
  for (int nt = 0; nt < 8; nt++) {
    float c = cm[nt];
    c = fmaxf(c, __shfl_xor(c, 16));
    c = fmaxf(c, __shfl_xor(c, 32));
    if (quad == 0) cmw[wave][nt * 16 + r16] = c;
  }
  __syncthreads();
  if (tid < NS) {
    float c = fmaxf(fmaxf(cmw[0][tid], cmw[1][tid]), fmaxf(cmw[2][tid], cmw[3][tid]));
    cm_part[(size_t)tid * (NB * NH) + bh] = c;  // [j][bh] layout, plain store
  }
}

// cm_part[j][0..1023] -> scl[392+j] = max (identical value set as the old atomics)
__global__ void colmax_reduce_kernel(const float* __restrict__ cm_part,
                                     u32* __restrict__ sclu) {
  int j = blockIdx.x;
  const float* row = cm_part + (size_t)j * (NB * NH);
  float m = 0.0f;
  for (int i = threadIdx.x; i < NB * NH; i += blockDim.x) m = fmaxf(m, row[i]);
  for (int off = 32; off; off >>= 1) m = fmaxf(m, __shfl_down(m, off));
  __shared__ float sm[4];
  if ((threadIdx.x & 63) == 0) sm[threadIdx.x >> 6] = m;
  __syncthreads();
  if (threadIdx.x == 0)
    sclu[392 + j] = __float_as_uint(fmaxf(fmaxf(sm[0], sm[1]), fmaxf(sm[2], sm[3])));
}

// Phase 2: recompute QK^T + softmax (bitwise-identical to phase 1), quantize P with
// final colmax scales into LDS (one 64-col half at a time), then PV.
// V prefetched to regs at entry (T14), K staged via global_load_lds, setprio
// around MFMA, ONE xmax atomic per block.
__global__ __launch_bounds__(256, 4)
void attn_pv2_kernel(const i8* __restrict__ qi8, const i8* __restrict__ ki8,
                     const i8* __restrict__ vi8, const u64* __restrict__ mb,
                     const float* __restrict__ scl, float* __restrict__ xout,
                     u32* __restrict__ xmax_slot) {
  const int bh = blockIdx.x, b = bh >> 4, h = bh & 15;
  const int tid = threadIdx.x, lane = tid & 63, wave = tid >> 6;
  const int r16 = lane & 15, quad = lane >> 4;
  const int rowbase = wave * 32;

  union SU {
    i8 K[NS][64];                                   // 8 KB packed (global_load_lds dest)
    struct { u16 hi[64][72]; u16 lo[64][72]; } v;   // 18.4 KB (PV phase)
  };
  __shared__ __align__(16) SU u;
  __shared__ __align__(16) u16 Ps[NS][72];  // 18 KB; holds one 64-col half at a time
  __shared__ float sqv[NS], skv[NS], spv[NS], svv[NS];
  __shared__ float xmw[4];

  // --- issue ALL global loads up front: V (both halves), Q frags, K via glds16 ---
  const int jl = tid >> 2, d0v = (tid & 3) * 16;
  const i8* vb = vi8 + (size_t)(b * NS + jl) * NDM + h * NDK + d0v;
  int4 vpre0 = *(const int4*)vb;                        // V rows 0..63
  int4 vpre1 = *(const int4*)(vb + (size_t)64 * NDM);   // V rows 64..127

  i32x4 aq[2];
  {
    const i8* qp = qi8 + (size_t)b * NS * NDM + h * NDK;
#pragma unroll
    for (int mt = 0; mt < 2; mt++)
      aq[mt] = *(const i32x4*)(qp + (size_t)(rowbase + mt * 16 + r16) * NDM + quad * 16);
    const int lrow = lane >> 2, lcol = (lane & 3) * 16;
#pragma unroll
    for (int p = 0; p < 2; p++) {
      int r = wave * 32 + p * 16;
      glds16(ki8 + (size_t)(b * NS + r + lrow) * NDM + h * NDK + lcol, &u.K[r][0]);
    }
    if (tid < NS) {
      sqv[tid] = fmaxf(scl[8 + tid], QEPS) / 127.0f;
      skv[tid] = fmaxf(scl[8 + 128 + tid], QEPS) / 127.0f;
      spv[tid] = fmaxf(scl[392 + tid], QEPS) / 127.0f;
      svv[tid] = fmaxf(scl[8 + 256 + tid], QEPS) / 127.0f;
    }
  }
  __syncthreads();

  i32x4 acc[2][8] = {};
  __builtin_amdgcn_s_setprio(1);
#pragma unroll
  for (int mt = 0; mt < 2; mt++) {
#pragma unroll
    for (int nt = 0; nt < 8; nt++) {
      i32x4 bfrag = *(const i32x4*)&u.K[nt * 16 + r16][quad * 16];
      acc[mt][nt] = __builtin_amdgcn_mfma_i32_16x16x64_i8(aq[mt], bfrag, acc[mt][nt], 0, 0, 0);
    }
  }
  __builtin_amdgcn_s_setprio(0);

  float skc[8], spc[8];
#pragma unroll
  for (int nt = 0; nt < 8; nt++) {
    skc[nt] = skv[nt * 16 + r16];
    spc[nt] = spv[nt * 16 + r16];
  }

  // Softmax (bitwise-identical to phase 1). Low half (cols 0-63) -> Ps now;
  // high half (cols 64-127) -> packed bf16 in registers, written after PV half 0.
  // Ps is wave-local (each wave touches only its own 32 rows), so no barrier needed.
  u32 pqh[2][4][2];
#pragma unroll
  for (int mt = 0; mt < 2; mt++) {
#pragma unroll
    for (int r = 0; r < 4; r++) {
      int row = rowbase + mt * 16 + quad * 4 + r;
      float sq = sqv[row];
      const u64* mrow = mb + ((size_t)b * NS + row) * 2;
      u64 m0 = mrow[0], m1 = mrow[1];
      float vals[8];
      float mx = -INFINITY;
#pragma unroll
      for (int nt = 0; nt < 8; nt++) {
        float v = (float)acc[mt][nt][r] * (sq * skc[nt]) * 0.125f;
        u64 bits = nt < 4 ? m0 : m1;
        if (((bits >> ((nt * 16 + r16) & 63)) & 1ull) == 0) v = -1e9f;
        vals[nt] = v;
        mx = fmaxf(mx, v);
      }
#pragma unroll
      for (int off = 1; off < 16; off <<= 1) mx = fmaxf(mx, __shfl_xor(mx, off));
      float sum = 0.0f;
#pragma unroll
      for (int nt = 0; nt < 8; nt++) { vals[nt] = __expf(vals[nt] - mx); sum += vals[nt]; }
#pragma unroll
      for (int off = 1; off < 16; off <<= 1) sum += __shfl_xor(sum, off);
#pragma unroll
      for (int nt = 0; nt < 4; nt++) {
        float p = vals[nt] / sum;  // bitwise equal to phase-1 p
        float pq = fminf(fmaxf(rintf(p / spc[nt]), -128.f), 127.f);
        Ps[row][nt * 16 + r16] = f2bf(pq);  // small ints: exact in bf16
      }
#pragma unroll
      for (int n2 = 0; n2 < 2; n2++) {
        float pa_ = vals[4 + n2 * 2] / sum;
        float pb_ = vals[5 + n2 * 2] / sum;
        float qa = fminf(fmaxf(rintf(pa_ / spc[4 + n2 * 2]), -128.f), 127.f);
        float qb = fminf(fmaxf(rintf(pb_ / spc[5 + n2 * 2]), -128.f), 127.f);
        pqh[mt][r][n2] = (u32)f2bf(qa) | ((u32)f2bf(qb) << 16);
      }
    }
  }

  f32x4 xacc[2][4] = {};
#pragma unroll
  for (int half = 0; half < 2; half++) {
    __syncthreads();  // half0: all waves done reading u.K; half1: done reading V half0
    {
      int j = half * 64 + jl;
      float g = spv[j] * svv[j];
      int4 raw = half ? vpre1 : vpre0;  // prefetched at entry; latency already hidden
      const i8* rb = (const i8*)&raw;
#pragma unroll
      for (int d = 0; d < 16; d++) {
        float w = (float)rb[d] * g;
        u16 hi = f2bf(w);
        u.v.hi[d0v + d][jl] = hi;
        u.v.lo[d0v + d][jl] = f2bf(w - bf2f(hi));
      }
    }
    __syncthreads();
    __builtin_amdgcn_s_setprio(1);
#pragma unroll
    for (int kk = 0; kk < 2; kk++) {
      short8 pa[2];
#pragma unroll
      for (int mt = 0; mt < 2; mt++)
        pa[mt] = *(const short8*)&Ps[rowbase + mt * 16 + r16][kk * 32 + quad * 8];
#pragma unroll
      for (int nt = 0; nt < 4; nt++) {
        short8 vh = *(const short8*)&u.v.hi[nt * 16 + r16][kk * 32 + quad * 8];
        short8 vl = *(const short8*)&u.v.lo[nt * 16 + r16][kk * 32 + quad * 8];
#pragma unroll
        for (int mt = 0; mt < 2; mt++) {
          xacc[mt][nt] = __builtin_amdgcn_mfma_f32_16x16x32_bf16(pa[mt], vh, xacc[mt][nt], 0, 0, 0);
          xacc[mt][nt] = __builtin_amdgcn_mfma_f32_16x16x32_bf16(pa[mt], vl, xacc[mt][nt], 0, 0, 0);
        }
      }
    }
    __builtin_amdgcn_s_setprio(0);
    if (half == 0) {
      // Overwrite Ps with cols 64-127 (wave-local rows; own reads above are done
      // in program order, other waves never touch these rows).
#pragma unroll
      for (int mt = 0; mt < 2; mt++)
#pragma unroll
        for (int r = 0; r < 4; r++) {
          int row = rowbase + mt * 16 + quad * 4 + r;
#pragma unroll
          for (int n2 = 0; n2 < 2; n2++) {
            u32 pk = pqh[mt][r][n2];
            Ps[row][(n2 * 2) * 16 + r16] = (u16)(pk & 0xFFFFu);
            Ps[row][(n2 * 2 + 1) * 16 + r16] = (u16)(pk >> 16);
          }
        }
    }
  }

  float mx = -INFINITY;
#pragma unroll
  for (int mt = 0; mt < 2; mt++)
#pragma unroll
    for (int nt = 0; nt < 4; nt++)
#pragma unroll
      for (int r = 0; r < 4; r++) {
        int row = rowbase + mt * 16 + quad * 4 + r;
        xout[((size_t)b * NS + row) * NDM + h * NDK + nt * 16 + r16] = xacc[mt][nt][r];
        mx = fmaxf(mx, xacc[mt][nt][r]);
      }
#pragma unroll
  for (int off = 1; off < 64; off <<= 1) mx = fmaxf(mx, __shfl_xor(mx, off));
  if (lane == 0) xmw[wave] = mx;
  __syncthreads();
  if (tid == 0) {
    float m = fmaxf(fmaxf(xmw[0], xmw[1]), fmaxf(xmw[2], xmw[3]));
    atomicMax(xmax_slot, fenc(m));  // 1 atomic/block (was 4)
  }
}

// ---------------- workspace layout ----------------
constexpr size_t OFF_SCL = 0;                                   // 8 KB (2048 u32)
constexpr size_t OFF_CS  = 8192;                                // colsum 4x1024 int = 16 KB
constexpr size_t OFF_MB  = OFF_CS + 4 * NDM * 4;                // mask bits 128 KB
constexpr size_t OFF_W   = OFF_MB + (size_t)NM * 16;            // i8 weights 4 MB
constexpr size_t OFF_XQ  = OFF_W + 4 * (size_t)NDM * NDM;       // i8 acts 3x8 MB
constexpr size_t OFF_PQ  = OFF_XQ + 3 * (size_t)NM * NDM;       // f32 proj 3x33.5 MB
constexpr size_t OFF_I8  = OFF_PQ + 3 * (size_t)NM * NDM * 4;   // attn i8 qkv 3x8 MB
constexpr size_t OFF_CM  = OFF_I8 + 3 * (size_t)NM * NDM;       // colmax scratch 512 KB
constexpr size_t OFF_RP  = OFF_CM + (size_t)NS * NB * NH * 4;   // rmax scratch 1.5 MB
// xout aliases projv (dead after qkv_i8); P is never materialized (flash recompute)

extern "C" void kernel_launch(void* const* d_in, const int* in_sizes, int n_in,
                              void* d_out, int out_size, void* d_ws, size_t ws_size,
                              hipStream_t stream) {
  const float* query = (const float*)d_in[0];
  const float* key = (const float*)d_in[1];
  const float* value = (const float*)d_in[2];
  const int* mask = (const int*)d_in[3];
  const float* Wq = (const float*)d_in[4]; const float* bq = (const float*)d_in[5];
  const float* Wk = (const float*)d_in[6]; const float* bk = (const float*)d_in[7];
  const float* Wv = (const float*)d_in[8]; const float* bv = (const float*)d_in[9];
  const float* Wo = (const float*)d_in[10]; const float* bo = (const float*)d_in[11];

  char* ws = (char*)d_ws;
  float* scl = (float*)(ws + OFF_SCL);
  u32* sclu = (u32*)scl;
  int* colsum = (int*)(ws + OFF_CS);
  u64* mb = (u64*)(ws + OFF_MB);
  i8* wb = (i8*)(ws + OFF_W);        // wq|wk|wv|wo
  i8* wob = wb + 3 * (size_t)NDM * NDM;
  i8* xq = (i8*)(ws + OFF_XQ);       // q|k|v shifted i8 (slot 0 reused for x)
  float* proj = (float*)(ws + OFF_PQ);
  i8* qkv8 = (i8*)(ws + OFF_I8);
  float* cm_part = (float*)(ws + OFF_CM);
  float* rmax_part = (float*)(ws + OFF_RP);
  float* xout = proj + 2 * (size_t)NM * NDM;
  i8* vi8 = qkv8 + 2 * (size_t)NM * NDM;

  maskbits_kernel<<<NM / 4, 256, 0, stream>>>(mask, mb, sclu);
  fused_max_kernel<<<dim3(512, 7), 256, 0, stream>>>(query, key, value, Wq, Wk, Wv, Wo, sclu);
  quant_w_i8_kernel<<<dim3(NDM, 4), 256, 0, stream>>>(Wq, Wk, Wv, Wo, wb, colsum, sclu);
  quant_a_kernel<<<dim3(512, 3), 256, 0, stream>>>(query, key, value, xq, sclu, 0);

  gemm_kernel<true><<<dim3(NM / BM, NDM / BN, 3), 256, 0, stream>>>(
      xq, wb, colsum, bq, bk, bv, proj, sclu, rmax_part);
  rmax_reduce_kernel<<<384, 256, 0, stream>>>(rmax_part, sclu);

  qkv_i8_kernel<<<dim3(512, 3), 256, 0, stream>>>(proj, qkv8, scl);

  attn_colmax_kernel<<<NB * NH, 256, 0, stream>>>(qkv8, qkv8 + (size_t)NM * NDM, mb, scl,
                                                  cm_part);
  colmax_reduce_kernel<<<NS, 256, 0, stream>>>(cm_part, sclu);
  attn_pv2_kernel<<<NB * NH, 256, 0, stream>>>(qkv8, qkv8 + (size_t)NM * NDM, vi8, mb, scl,
                                               xout, sclu + 7);

  quant_a_kernel<<<dim3(512, 1), 256, 0, stream>>>(xout, xout, xout, xq, sclu, 7);
  gemm_kernel<false><<<dim3(NM / BM, NDM / BN, 1), 256, 0, stream>>>(
      xq, wob, colsum, bo, bo, bo, (float*)d_out, sclu, rmax_part);
}

// Round 9
// 384.764 us; speedup vs baseline: 1.0159x; 1.0159x over previous
//
#include <hip/hip_runtime.h>
#include <hip/hip_bf16.h>
#include <hip/hip_cooperative_groups.h>
#include <math.h>

namespace cg = cooperative_groups;

typedef unsigned short u16;
typedef unsigned int u32;
typedef unsigned long long u64;
typedef signed char i8;

constexpr int NB = 64, NS = 128, NDM = 1024, NH = 16, NDK = 64;
constexpr int NM = NB * NS;  // 8192
constexpr float QEPS = 1e-8f;

typedef __attribute__((ext_vector_type(8))) short short8;
typedef __attribute__((ext_vector_type(4))) float f32x4;
typedef __attribute__((ext_vector_type(4))) int i32x4;

__device__ __forceinline__ u32 fenc(float f) {
  u32 u = __float_as_uint(f);
  return (u & 0x80000000u) ? ~u : (u | 0x80000000u);
}
__device__ __forceinline__ float fdec(u32 u) {
  u = (u & 0x80000000u) ? (u & 0x7FFFFFFFu) : ~u;
  return __uint_as_float(u);
}
// quantized values are small integers -> exact bf16 truncation
__device__ __forceinline__ u16 f2bf(float f) { return (u16)(__float_as_uint(f) >> 16); }
__device__ __forceinline__ float bf2f(u16 u) { return __uint_as_float(((u32)u) << 16); }

// async global->LDS, 16B per lane; lds dest = wave-uniform base + lane*16
__device__ __forceinline__ void glds16(const void* g, void* l) {
  __builtin_amdgcn_global_load_lds(
      (const __attribute__((address_space(1))) void*)(unsigned long long)(uintptr_t)g,
      (__attribute__((address_space(3))) void*)(u32)(uintptr_t)l, 16, 0, 0);
}

// ---- scale slots (u32/float at ws offset 0) ----
// [0..2] enc max(q,k,v)  [3..6] enc absmax(W*)  [7] enc max(x)
// [8..135] absmax_q per s; [136..263] absmax_k; [264..391] absmax_v (plain float bits)
// [392..519] colmax_p per j (fallback path); [1024..1151] colmax_p per j (fused path,
// fresh cache lines — entry-time loads never touch them)

// mask[B,S,S] int32 -> bitmask [B*S][2] u64; block 0 also zeroes the scale slots
__global__ void maskbits_kernel(const int* __restrict__ mask, u64* __restrict__ mb,
                                u32* __restrict__ scl) {
  if (blockIdx.x == 0) {
    for (int i = threadIdx.x; i < 2048; i += blockDim.x) scl[i] = 0u;
  }
  int row = blockIdx.x * 4 + (threadIdx.x >> 6);
  int lane = threadIdx.x & 63;
  const int* mrow = mask + (size_t)row * NS;
  u64 b0 = __ballot(mrow[lane] != 0);
  u64 b1 = __ballot(mrow[64 + lane] != 0);
  if (lane == 0) { mb[row * 2] = b0; mb[row * 2 + 1] = b1; }
}

// fused 7-way max reduce: y=0..2 max(q,k,v); y=3..6 absmax(Wq..Wo)
__global__ void fused_max_kernel(const float* __restrict__ q, const float* __restrict__ k,
                                 const float* __restrict__ v, const float* __restrict__ w0,
                                 const float* __restrict__ w1, const float* __restrict__ w2,
                                 const float* __restrict__ w3, u32* __restrict__ sclu) {
  int y = blockIdx.y;
  const float* src; size_t n4; int ab;
  switch (y) {
    case 0: src = q; n4 = (size_t)NM * NDM / 4; ab = 0; break;
    case 1: src = k; n4 = (size_t)NM * NDM / 4; ab = 0; break;
    case 2: src = v; n4 = (size_t)NM * NDM / 4; ab = 0; break;
    case 3: src = w0; n4 = (size_t)NDM * NDM / 4; ab = 1; break;
    case 4: src = w1; n4 = (size_t)NDM * NDM / 4; ab = 1; break;
    case 5: src = w2; n4 = (size_t)NDM * NDM / 4; ab = 1; break;
    default: src = w3; n4 = (size_t)NDM * NDM / 4; ab = 1; break;
  }
  float m = -INFINITY;
  size_t stride = (size_t)gridDim.x * blockDim.x;
  for (size_t i = (size_t)blockIdx.x * blockDim.x + threadIdx.x; i < n4; i += stride) {
    float4 f = ((const float4*)src)[i];
    if (ab) { f.x = fabsf(f.x); f.y = fabsf(f.y); f.z = fabsf(f.z); f.w = fabsf(f.w); }
    m = fmaxf(m, fmaxf(fmaxf(f.x, f.y), fmaxf(f.z, f.w)));
  }
  for (int off = 32; off; off >>= 1) m = fmaxf(m, __shfl_down(m, off));
  __shared__ float sm[4];
  if ((threadIdx.x & 63) == 0) sm[threadIdx.x >> 6] = m;
  __syncthreads();
  if (threadIdx.x == 0) {
    float r = fmaxf(fmaxf(sm[0], sm[1]), fmaxf(sm[2], sm[3]));
    atomicMax(&sclu[y], fenc(r));
  }
}

// weight quant -> i8 (-127..127) + per-output-channel column sums (for u8 shift fix)
__global__ __launch_bounds__(256)
void quant_w_i8_kernel(const float* __restrict__ w0, const float* __restrict__ w1,
                       const float* __restrict__ w2, const float* __restrict__ w3,
                       i8* __restrict__ dst, int* __restrict__ colsum,
                       const u32* __restrict__ sclu) {
  int y = blockIdx.y, row = blockIdx.x, tid = threadIdx.x;
  const float* src = (y == 0 ? w0 : y == 1 ? w1 : y == 2 ? w2 : w3) + (size_t)row * NDM;
  float s = fmaxf(fdec(sclu[3 + y]), QEPS) / 127.0f;
  float4 f = ((const float4*)src)[tid];
  int a = (int)fminf(fmaxf(rintf(f.x / s), -127.f), 127.f);
  int b = (int)fminf(fmaxf(rintf(f.y / s), -127.f), 127.f);
  int c = (int)fminf(fmaxf(rintf(f.z / s), -127.f), 127.f);
  int d = (int)fminf(fmaxf(rintf(f.w / s), -127.f), 127.f);
  ((int*)(dst + (size_t)y * NDM * NDM + (size_t)row * NDM))[tid] =
      (a & 255) | ((b & 255) << 8) | ((c & 255) << 16) | ((d & 255) << 24);
  int ssum = a + b + c + d;
  for (int off = 32; off; off >>= 1) ssum += __shfl_down(ssum, off);
  __shared__ int sm[4];
  if ((tid & 63) == 0) sm[tid >> 6] = ssum;
  __syncthreads();
  if (tid == 0) colsum[y * NDM + row] = sm[0] + sm[1] + sm[2] + sm[3];
}

// uint8 activation fake-quant -> shifted i8 (q-128); y selects source/slot/dst
__global__ void quant_a_kernel(const float* __restrict__ s0, const float* __restrict__ s1,
                               const float* __restrict__ s2, i8* __restrict__ dst,
                               const u32* __restrict__ sclu, int slot_base) {
  int y = blockIdx.y;
  const float* src = y == 0 ? s0 : y == 1 ? s1 : s2;
  i8* d = dst + (size_t)y * NM * NDM;
  float s = fmaxf(fdec(sclu[slot_base + y]), QEPS) / 255.0f;
  size_t n4 = (size_t)NM * NDM / 4;
  size_t stride = (size_t)gridDim.x * blockDim.x;
  for (size_t i = (size_t)blockIdx.x * blockDim.x + threadIdx.x; i < n4; i += stride) {
    float4 f = ((const float4*)src)[i];
    int a = (int)fminf(fmaxf(rintf(f.x / s), 0.f), 255.f) - 128;
    int b = (int)fminf(fmaxf(rintf(f.y / s), 0.f), 255.f) - 128;
    int c = (int)fminf(fmaxf(rintf(f.z / s), 0.f), 255.f) - 128;
    int e = (int)fminf(fmaxf(rintf(f.w / s), 0.f), 255.f) - 128;
    ((int*)d)[i] = (a & 255) | ((b & 255) << 8) | ((c & 255) << 16) | ((e & 255) << 24);
  }
}

// proj fp32 -> int8 with per-s scale; y=0..2 selects q/k/v
__global__ void qkv_i8_kernel(const float* __restrict__ projbase, i8* __restrict__ dstbase,
                              const float* __restrict__ scl) {
  int y = blockIdx.y;
  const float* src = projbase + (size_t)y * NM * NDM;
  i8* dst = dstbase + (size_t)y * NM * NDM;
  const float* sb = scl + 8 + y * 128;
  size_t n4 = (size_t)NM * NDM / 4;
  size_t stride = (size_t)gridDim.x * blockDim.x;
  for (size_t i = (size_t)blockIdx.x * blockDim.x + threadIdx.x; i < n4; i += stride) {
    int s_idx = (int)((i >> 8) & 127);
    float s = fmaxf(sb[s_idx], QEPS) / 127.0f;
    float4 f = ((const float4*)src)[i];
    int a = (int)fminf(fmaxf(rintf(f.x / s), -128.f), 127.f);
    int b = (int)fminf(fmaxf(rintf(f.y / s), -128.f), 127.f);
    int c = (int)fminf(fmaxf(rintf(f.z / s), -128.f), 127.f);
    int d = (int)fminf(fmaxf(rintf(f.w / s), -128.f), 127.f);
    ((int*)dst)[i] = (a & 255) | ((b & 255) << 8) | ((c & 255) << 16) | ((d & 255) << 24);
  }
}

// ---------------- GEMM: i8 MFMA, dbuf glds16, 64x32 wave tile ----------------
constexpr int BM = 128, BN = 64, BK = 64, KTILES = NDM / BK;

template <bool PROJ>
__global__ __launch_bounds__(256, 4)
void gemm_kernel(const i8* __restrict__ Abase, const i8* __restrict__ Wbase,
                 const int* __restrict__ colsum, const float* __restrict__ b0,
                 const float* __restrict__ b1, const float* __restrict__ b2,
                 float* __restrict__ Cbase, u32* __restrict__ sclu,
                 float* __restrict__ rmax_part) {
  constexpr int K = NDM, N = NDM;
  const int z = PROJ ? blockIdx.z : 0;
  const i8* A = Abase + (size_t)z * NM * NDM;
  const i8* Wt = PROJ ? (Wbase + (size_t)z * NDM * NDM) : Wbase;
  const float* bias = PROJ ? (z == 0 ? b0 : z == 1 ? b1 : b2) : b0;
  float* C = PROJ ? (Cbase + (size_t)z * NM * NDM) : Cbase;
  const u32* slot_in = PROJ ? (sclu + z) : (sclu + 7);
  const u32* slot_w = PROJ ? (sclu + 3 + z) : (sclu + 6);
  const int* cs = colsum + (PROJ ? z : 3) * NDM;

  __shared__ __align__(16) i8 As[2][BM][BK];  // 16 KB (dbuf)
  __shared__ __align__(16) i8 Bs[2][BN][BK];  // 8 KB (dbuf)
  __shared__ float rmax2[4][64];

  const int tid = threadIdx.x;
  const int lane = tid & 63, wave = tid >> 6;
  const int wm = (wave & 1) * 64, wn = (wave >> 1) * 32;
  const int r16 = lane & 15, quad = lane >> 4;
  const int bm = blockIdx.x * BM, bn = blockIdx.y * BN;

  const int lrow = lane >> 2, lcol = (lane & 3) * 16;  // 16 rows per glds16, 64B rows
  const i8* Ab = A + (size_t)(bm + wave * 32 + lrow) * K + lcol;
  const i8* Bb = Wt + (size_t)(bn + wave * 16 + lrow) * K + lcol;

  i32x4 acc[4][2] = {};

  // prologue: stage tile 0
  glds16(Ab, &As[0][wave * 32][0]);
  glds16(Ab + (size_t)16 * K, &As[0][wave * 32 + 16][0]);
  glds16(Bb, &Bs[0][wave * 16][0]);
  __syncthreads();

  int cur = 0;
  for (int t = 0; t < KTILES; t++) {
    if (t + 1 < KTILES) {  // issue next tile's loads BEFORE computing current
      int k0 = (t + 1) * BK;
      glds16(Ab + k0, &As[cur ^ 1][wave * 32][0]);
      glds16(Ab + (size_t)16 * K + k0, &As[cur ^ 1][wave * 32 + 16][0]);
      glds16(Bb + k0, &Bs[cur ^ 1][wave * 16][0]);
    }
    i32x4 af[4], bfr[2];
#pragma unroll
    for (int i = 0; i < 4; i++)
      af[i] = *(const i32x4*)(&As[cur][wm + i * 16 + r16][quad * 16]);
#pragma unroll
    for (int j = 0; j < 2; j++)
      bfr[j] = *(const i32x4*)(&Bs[cur][wn + j * 16 + r16][quad * 16]);
#pragma unroll
    for (int i = 0; i < 4; i++)
#pragma unroll
      for (int j = 0; j < 2; j++)
        acc[i][j] = __builtin_amdgcn_mfma_i32_16x16x64_i8(af[i], bfr[j], acc[i][j], 0, 0, 0);
    __syncthreads();  // drains this iter's prefetch (vmcnt0) + fences buffer reuse
    cur ^= 1;
  }

  float s_in = fmaxf(fdec(*slot_in), QEPS) / 255.0f;
  float s_w = fmaxf(fdec(*slot_w), QEPS) / 127.0f;
  float sc = s_in * s_w;

  float bq[2];
  int csj[2];
#pragma unroll
  for (int j = 0; j < 2; j++) {
    int gc = bn + wn + j * 16 + r16;
    bq[j] = rintf(bias[gc] / sc) * sc;
    csj[j] = cs[gc] << 7;  // +128 * colsum(W): undoes the x-128 input shift
  }
#pragma unroll
  for (int i = 0; i < 4; i++) {
#pragma unroll
    for (int r = 0; r < 4; r++) {
      int l64 = i * 16 + quad * 4 + r;  // 0..63 within wave-M group
      int gr = bm + wm + l64;
      float rm = 0.0f;
#pragma unroll
      for (int j = 0; j < 2; j++) {
        int gc = bn + wn + j * 16 + r16;
        float val = (float)(acc[i][j][r] + csj[j]) * sc + bq[j];
        C[(size_t)gr * N + gc] = val;
        if (PROJ) rm = fmaxf(rm, fabsf(val));
      }
      if (PROJ) {
#pragma unroll
        for (int off = 1; off < 16; off <<= 1) rm = fmaxf(rm, __shfl_xor(rm, off));
        if (r16 == 0) rmax2[wave][l64] = rm;
      }
    }
  }
  if (PROJ) {
    // per-block rowmax vector -> scratch (coalesced store; NO atomics)
    __syncthreads();
    if (tid < BM) {
      int g = tid >> 6, l = tid & 63;  // waves {g, g+2} share wm group g
      float m = fmaxf(rmax2[g][l], rmax2[g + 2][l]);
      int blockId = z * 1024 + blockIdx.x * 16 + blockIdx.y;
      rmax_part[(size_t)blockId * 128 + tid] = m;
    }
  }
}

// rmax_part[z*1024 + b][lr] -> scl[8 + z*128 + lr] = max over b
__global__ void rmax_reduce_kernel(const float* __restrict__ part, u32* __restrict__ sclu) {
  int slot = blockIdx.x;  // 0..383
  int z = slot >> 7, lr = slot & 127;
  const float* base = part + (size_t)z * 1024 * 128 + lr;
  float m = 0.0f;
  for (int i = threadIdx.x; i < 1024; i += blockDim.x) m = fmaxf(m, base[(size_t)i * 128]);
  for (int off = 32; off; off >>= 1) m = fmaxf(m, __shfl_down(m, off));
  __shared__ float sm[4];
  if ((threadIdx.x & 63) == 0) sm[threadIdx.x >> 6] = m;
  __syncthreads();
  if (threadIdx.x == 0)
    sclu[8 + slot] = __float_as_uint(fmaxf(fmaxf(sm[0], sm[1]), fmaxf(sm[2], sm[3])));
}

// ---------------- attention: FUSED cooperative kernel ----------------
// One pass: QK^T + softmax (P kept in registers) -> per-block colmax -> grid.sync ->
// 128 reducer blocks finalize colmax -> grid.sync -> quantize P -> PV.
// Cross-XCD handoffs via agent-scope atomics (G16). Colmax slots at 1024+ (fresh lines).
__global__ __launch_bounds__(256, 4)
void attn_fused_kernel(const i8* __restrict__ qi8, const i8* __restrict__ ki8,
                       const i8* __restrict__ vi8, const u64* __restrict__ mb,
                       const float* __restrict__ scl, u32* __restrict__ sclu,
                       float* __restrict__ cm_part, float* __restrict__ xout,
                       u32* __restrict__ xmax_slot) {
  const int bh = blockIdx.x, b = bh >> 4, h = bh & 15;
  const int tid = threadIdx.x, lane = tid & 63, wave = tid >> 6;
  const int r16 = lane & 15, quad = lane >> 4;
  const int rowbase = wave * 32;

  union SU {
    struct { i8 K[NS][64]; float cmw[4][NS]; } qk;  // 10.25 KB (phase 1)
    struct { u16 hi[64][72]; u16 lo[64][72]; } v;   // 18.4 KB (PV phase)
  };
  __shared__ __align__(16) SU u;
  __shared__ __align__(16) u16 Ps[NS][72];  // 18 KB; one 64-col half at a time
  __shared__ float sqv[NS], skv[NS], svv[NS], spv[NS];
  __shared__ float xmw[4];

  // --- entry: V both halves -> regs, Q frags -> regs, K via glds16, static scales ---
  const int jl = tid >> 2, d0v = (tid & 3) * 16;
  const i8* vb = vi8 + (size_t)(b * NS + jl) * NDM + h * NDK + d0v;
  int4 vpre0 = *(const int4*)vb;
  int4 vpre1 = *(const int4*)(vb + (size_t)64 * NDM);

  i32x4 aq[2];
  {
    const i8* qp = qi8 + (size_t)b * NS * NDM + h * NDK;
#pragma unroll
    for (int mt = 0; mt < 2; mt++)
      aq[mt] = *(const i32x4*)(qp + (size_t)(rowbase + mt * 16 + r16) * NDM + quad * 16);
    const int lrow = lane >> 2, lcol = (lane & 3) * 16;
#pragma unroll
    for (int p = 0; p < 2; p++) {
      int r = wave * 32 + p * 16;
      glds16(ki8 + (size_t)(b * NS + r + lrow) * NDM + h * NDK + lcol, &u.qk.K[r][0]);
    }
    if (tid < NS) {
      sqv[tid] = fmaxf(scl[8 + tid], QEPS) / 127.0f;
      skv[tid] = fmaxf(scl[8 + 128 + tid], QEPS) / 127.0f;
      svv[tid] = fmaxf(scl[8 + 256 + tid], QEPS) / 127.0f;
    }
  }
  __syncthreads();

  i32x4 acc[2][8] = {};
  __builtin_amdgcn_s_setprio(1);
#pragma unroll
  for (int mt = 0; mt < 2; mt++) {
#pragma unroll
    for (int nt = 0; nt < 8; nt++) {
      i32x4 bfrag = *(const i32x4*)&u.qk.K[nt * 16 + r16][quad * 16];
      acc[mt][nt] = __builtin_amdgcn_mfma_i32_16x16x64_i8(aq[mt], bfrag, acc[mt][nt], 0, 0, 0);
    }
  }
  __builtin_amdgcn_s_setprio(0);

  float skc[8];
#pragma unroll
  for (int nt = 0; nt < 8; nt++) skc[nt] = skv[nt * 16 + r16];

  // softmax ONCE; keep normalized P in registers; track per-column max
  float p[2][4][8];
  float cm[8] = {0.f, 0.f, 0.f, 0.f, 0.f, 0.f, 0.f, 0.f};
#pragma unroll
  for (int mt = 0; mt < 2; mt++) {
#pragma unroll
    for (int r = 0; r < 4; r++) {
      int row = rowbase + mt * 16 + quad * 4 + r;
      float sq = sqv[row];
      const u64* mrow = mb + ((size_t)b * NS + row) * 2;
      u64 m0 = mrow[0], m1 = mrow[1];
      float vals[8];
      float mx = -INFINITY;
#pragma unroll
      for (int nt = 0; nt < 8; nt++) {
        float v = (float)acc[mt][nt][r] * (sq * skc[nt]) * 0.125f;
        u64 bits = nt < 4 ? m0 : m1;
        if (((bits >> ((nt * 16 + r16) & 63)) & 1ull) == 0) v = -1e9f;
        vals[nt] = v;
        mx = fmaxf(mx, v);
      }
#pragma unroll
      for (int off = 1; off < 16; off <<= 1) mx = fmaxf(mx, __shfl_xor(mx, off));
      float sum = 0.0f;
#pragma unroll
      for (int nt = 0; nt < 8; nt++) { vals[nt] = __expf(vals[nt] - mx); sum += vals[nt]; }
#pragma unroll
      for (int off = 1; off < 16; off <<= 1) sum += __shfl_xor(sum, off);
#pragma unroll
      for (int nt = 0; nt < 8; nt++) {
        float pv_ = vals[nt] / sum;
        p[mt][r][nt] = pv_;
        cm[nt] = fmaxf(cm[nt], pv_);
      }
    }
  }

  // per-block colmax -> cm_part[bh][j] (coalesced agent-scope stores)
#pragma unroll
  for (int nt = 0; nt < 8; nt++) {
    float c = cm[nt];
    c = fmaxf(c, __shfl_xor(c, 16));
    c = fmaxf(c, __shfl_xor(c, 32));
    if (quad == 0) u.qk.cmw[wave][nt * 16 + r16] = c;
  }
  __syncthreads();
  if (tid < NS) {
    float c = fmaxf(fmaxf(u.qk.cmw[0][tid], u.qk.cmw[1][tid]),
                    fmaxf(u.qk.cmw[2][tid], u.qk.cmw[3][tid]));
    __hip_atomic_store(&cm_part[(size_t)bh * NS + tid], c, __ATOMIC_RELAXED,
                       __HIP_MEMORY_SCOPE_AGENT);
  }

  cg::this_grid().sync();  // all colmax partials visible

  if (bh < NS) {  // reducer block for column j = bh
    float m = 0.0f;
    for (int i = tid; i < NB * NH; i += 256)
      m = fmaxf(m, __hip_atomic_load(&cm_part[(size_t)i * NS + bh], __ATOMIC_RELAXED,
                                     __HIP_MEMORY_SCOPE_AGENT));
#pragma unroll
    for (int off = 32; off; off >>= 1) m = fmaxf(m, __shfl_down(m, off));
    if (lane == 0) xmw[wave] = m;
    __syncthreads();
    if (tid == 0) {
      float mm = fmaxf(fmaxf(xmw[0], xmw[1]), fmaxf(xmw[2], xmw[3]));
      __hip_atomic_store(&sclu[1024 + bh], __float_as_uint(mm), __ATOMIC_RELAXED,
                         __HIP_MEMORY_SCOPE_AGENT);
    }
  }

  cg::this_grid().sync();  // final colmax visible

  if (tid < NS) {
    u32 cu = __hip_atomic_load(&sclu[1024 + tid], __ATOMIC_RELAXED,
                               __HIP_MEMORY_SCOPE_AGENT);
    spv[tid] = fmaxf(__uint_as_float(cu), QEPS) / 127.0f;
  }
  __syncthreads();

  float spc[8];
#pragma unroll
  for (int nt = 0; nt < 8; nt++) spc[nt] = spv[nt * 16 + r16];

  // quantize P from registers: low half -> Ps (wave-local rows), high half -> pqh regs
  u32 pqh[2][4][2];
#pragma unroll
  for (int mt = 0; mt < 2; mt++) {
#pragma unroll
    for (int r = 0; r < 4; r++) {
      int row = rowbase + mt * 16 + quad * 4 + r;
#pragma unroll
      for (int nt = 0; nt < 4; nt++) {
        float pq = fminf(fmaxf(rintf(p[mt][r][nt] / spc[nt]), -128.f), 127.f);
        Ps[row][nt * 16 + r16] = f2bf(pq);  // small ints: exact in bf16
      }
#pragma unroll
      for (int n2 = 0; n2 < 2; n2++) {
        float qa = fminf(fmaxf(rintf(p[mt][r][4 + n2 * 2] / spc[4 + n2 * 2]), -128.f), 127.f);
        float qb = fminf(fmaxf(rintf(p[mt][r][5 + n2 * 2] / spc[5 + n2 * 2]), -128.f), 127.f);
        pqh[mt][r][n2] = (u32)f2bf(qa) | ((u32)f2bf(qb) << 16);
      }
    }
  }

  f32x4 xacc[2][4] = {};
#pragma unroll
  for (int half = 0; half < 2; half++) {
    __syncthreads();  // half0: K/cmw reads done (pre-sync1); half1: V half0 reads done
    {
      int j = half * 64 + jl;
      float g = spv[j] * svv[j];
      int4 raw = half ? vpre1 : vpre0;
      const i8* rb = (const i8*)&raw;
#pragma unroll
      for (int d = 0; d < 16; d++) {
        float w = (float)rb[d] * g;
        u16 hi = f2bf(w);
        u.v.hi[d0v + d][jl] = hi;
        u.v.lo[d0v + d][jl] = f2bf(w - bf2f(hi));
      }
    }
    __syncthreads();
    __builtin_amdgcn_s_setprio(1);
#pragma unroll
    for (int kk = 0; kk < 2; kk++) {
      short8 pa[2];
#pragma unroll
      for (int mt = 0; mt < 2; mt++)
        pa[mt] = *(const short8*)&Ps[rowbase + mt * 16 + r16][kk * 32 + quad * 8];
#pragma unroll
      for (int nt = 0; nt < 4; nt++) {
        short8 vh = *(const short8*)&u.v.hi[nt * 16 + r16][kk * 32 + quad * 8];
        short8 vl = *(const short8*)&u.v.lo[nt * 16 + r16][kk * 32 + quad * 8];
#pragma unroll
        for (int mt = 0; mt < 2; mt++) {
          xacc[mt][nt] = __builtin_amdgcn_mfma_f32_16x16x32_bf16(pa[mt], vh, xacc[mt][nt], 0, 0, 0);
          xacc[mt][nt] = __builtin_amdgcn_mfma_f32_16x16x32_bf16(pa[mt], vl, xacc[mt][nt], 0, 0, 0);
        }
      }
    }
    __builtin_amdgcn_s_setprio(0);
    if (half == 0) {
      // overwrite Ps with cols 64-127 (wave-local rows; program order per wave)
#pragma unroll
      for (int mt = 0; mt < 2; mt++)
#pragma unroll
        for (int r = 0; r < 4; r++) {
          int row = rowbase + mt * 16 + quad * 4 + r;
#pragma unroll
          for (int n2 = 0; n2 < 2; n2++) {
            u32 pk = pqh[mt][r][n2];
            Ps[row][(n2 * 2) * 16 + r16] = (u16)(pk & 0xFFFFu);
            Ps[row][(n2 * 2 + 1) * 16 + r16] = (u16)(pk >> 16);
          }
        }
    }
  }

  float mx = -INFINITY;
#pragma unroll
  for (int mt = 0; mt < 2; mt++)
#pragma unroll
    for (int nt = 0; nt < 4; nt++)
#pragma unroll
      for (int r = 0; r < 4; r++) {
        int row = rowbase + mt * 16 + quad * 4 + r;
        xout[((size_t)b * NS + row) * NDM + h * NDK + nt * 16 + r16] = xacc[mt][nt][r];
        mx = fmaxf(mx, xacc[mt][nt][r]);
      }
#pragma unroll
  for (int off = 1; off < 64; off <<= 1) mx = fmaxf(mx, __shfl_xor(mx, off));
  if (lane == 0) xmw[wave] = mx;
  __syncthreads();
  if (tid == 0) {
    float m = fmaxf(fmaxf(xmw[0], xmw[1]), fmaxf(xmw[2], xmw[3]));
    atomicMax(xmax_slot, fenc(m));
  }
}

// ---------------- attention: FALLBACK 3-kernel path (proven; unchanged) ----------------
__global__ __launch_bounds__(256)
void attn_colmax_kernel(const i8* __restrict__ qi8, const i8* __restrict__ ki8,
                        const u64* __restrict__ mb, const float* __restrict__ scl,
                        float* __restrict__ cm_part) {
  const int bh = blockIdx.x, b = bh >> 4, h = bh & 15;
  const int tid = threadIdx.x, lane = tid & 63, wave = tid >> 6;
  const int r16 = lane & 15, quad = lane >> 4;

  __shared__ __align__(16) i8 Qs[NS][80];
  __shared__ __align__(16) i8 Ks[NS][80];
  __shared__ float sqv[NS], skv[NS];
  __shared__ float cmw[4][NS];

  {
    int row = tid >> 1, half = (tid & 1) * 32;
    const i8* qp = qi8 + (size_t)(b * NS + row) * NDM + h * NDK + half;
    const i8* kp = ki8 + (size_t)(b * NS + row) * NDM + h * NDK + half;
    *(int4*)&Qs[row][half] = *(const int4*)qp;
    *(int4*)&Qs[row][half + 16] = *(const int4*)(qp + 16);
    *(int4*)&Ks[row][half] = *(const int4*)kp;
    *(int4*)&Ks[row][half + 16] = *(const int4*)(kp + 16);
    if (tid < NS) {
      sqv[tid] = fmaxf(scl[8 + tid], QEPS) / 127.0f;
      skv[tid] = fmaxf(scl[8 + 128 + tid], QEPS) / 127.0f;
    }
  }
  __syncthreads();

  const int rowbase = wave * 32;
  i32x4 acc[2][8] = {};
#pragma unroll
  for (int mt = 0; mt < 2; mt++) {
    i32x4 a = *(const i32x4*)&Qs[rowbase + mt * 16 + r16][quad * 16];
#pragma unroll
    for (int nt = 0; nt < 8; nt++) {
      i32x4 bfrag = *(const i32x4*)&Ks[nt * 16 + r16][quad * 16];
      acc[mt][nt] = __builtin_amdgcn_mfma_i32_16x16x64_i8(a, bfrag, acc[mt][nt], 0, 0, 0);
    }
  }

  float skc[8], cm[8];
#pragma unroll
  for (int nt = 0; nt < 8; nt++) { skc[nt] = skv[nt * 16 + r16]; cm[nt] = 0.0f; }

#pragma unroll
  for (int mt = 0; mt < 2; mt++) {
#pragma unroll
    for (int r = 0; r < 4; r++) {
      int row = rowbase + mt * 16 + quad * 4 + r;
      float sq = sqv[row];
      const u64* mrow = mb + ((size_t)b * NS + row) * 2;
      u64 m0 = mrow[0], m1 = mrow[1];
      float vals[8];
      float mx = -INFINITY;
#pragma unroll
      for (int nt = 0; nt < 8; nt++) {
        float v = (float)acc[mt][nt][r] * (sq * skc[nt]) * 0.125f;
        u64 bits = nt < 4 ? m0 : m1;
        if (((bits >> ((nt * 16 + r16) & 63)) & 1ull) == 0) v = -1e9f;
        vals[nt] = v;
        mx = fmaxf(mx, v);
      }
#pragma unroll
      for (int off = 1; off < 16; off <<= 1) mx = fmaxf(mx, __shfl_xor(mx, off));
      float sum = 0.0f;
#pragma unroll
      for (int nt = 0; nt < 8; nt++) { vals[nt] = __expf(vals[nt] - mx); sum += vals[nt]; }
#pragma unroll
      for (int off = 1; off < 16; off <<= 1) sum += __shfl_xor(sum, off);
#pragma unroll
      for (int nt = 0; nt < 8; nt++) {
        float p = vals[nt] / sum;
        cm[nt] = fmaxf(cm[nt], p);
      }
    }
  }

#pragma unroll
  for (int nt = 0; nt < 8; nt++) {
    float c = cm[nt];
    c = fmaxf(c, __shfl_xor(c, 16));
    c = fmaxf(c, __shfl_xor(c, 32));
    if (quad == 0) cmw[wave][nt * 16 + r16] = c;
  }
  __syncthreads();
  if (tid < NS) {
    float c = fmaxf(fmaxf(cmw[0][tid], cmw[1][tid]), fmaxf(cmw[2][tid], cmw[3][tid]));
    cm_part[(size_t)tid * (NB * NH) + bh] = c;
  }
}

__global__ void colmax_reduce_kernel(const float* __restrict__ cm_part,
                                     u32* __restrict__ sclu) {
  int j = blockIdx.x;
  const float* row = cm_part + (size_t)j * (NB * NH);
  float m = 0.0f;
  for (int i = threadIdx.x; i < NB * NH; i += blockDim.x) m = fmaxf(m, row[i]);
  for (int off = 32; off; off >>= 1) m = fmaxf(m, __shfl_down(m, off));
  __shared__ float sm[4];
  if ((threadIdx.x & 63) == 0) sm[threadIdx.x >> 6] = m;
  __syncthreads();
  if (threadIdx.x == 0)
    sclu[392 + j] = __float_as_uint(fmaxf(fmaxf(sm[0], sm[1]), fmaxf(sm[2], sm[3])));
}

__global__ __launch_bounds__(256, 4)
void attn_pv2_kernel(const i8* __restrict__ qi8, const i8* __restrict__ ki8,
                     const i8* __restrict__ vi8, const u64* __restrict__ mb,
                     const float* __restrict__ scl, float* __restrict__ xout,
                     u32* __restrict__ xmax_slot) {
  const int bh = blockIdx.x, b = bh >> 4, h = bh & 15;
  const int tid = threadIdx.x, lane = tid & 63, wave = tid >> 6;
  const int r16 = lane & 15, quad = lane >> 4;
  const int rowbase = wave * 32;

  union SU {
    i8 K[NS][64];
    struct { u16 hi[64][72]; u16 lo[64][72]; } v;
  };
  __shared__ __align__(16) SU u;
  __shared__ __align__(16) u16 Ps[NS][72];
  __shared__ float sqv[NS], skv[NS], spv[NS], svv[NS];
  __shared__ float xmw[4];

  const int jl = tid >> 2, d0v = (tid & 3) * 16;
  const i8* vb = vi8 + (size_t)(b * NS + jl) * NDM + h * NDK + d0v;
  int4 vpre0 = *(const int4*)vb;
  int4 vpre1 = *(const int4*)(vb + (size_t)64 * NDM);

  i32x4 aq[2];
  {
    const i8* qp = qi8 + (size_t)b * NS * NDM + h * NDK;
#pragma unroll
    for (int mt = 0; mt < 2; mt++)
      aq[mt] = *(const i32x4*)(qp + (size_t)(rowbase + mt * 16 + r16) * NDM + quad * 16);
    const int lrow = lane >> 2, lcol = (lane & 3) * 16;
#pragma unroll
    for (int p = 0; p < 2; p++) {
      int r = wave * 32 + p * 16;
      glds16(ki8 + (size_t)(b * NS + r + lrow) * NDM + h * NDK + lcol, &u.K[r][0]);
    }
    if (tid < NS) {
      sqv[tid] = fmaxf(scl[8 + tid], QEPS) / 127.0f;
      skv[tid] = fmaxf(scl[8 + 128 + tid], QEPS) / 127.0f;
      spv[tid] = fmaxf(scl[392 + tid], QEPS) / 127.0f;
      svv[tid] = fmaxf(scl[8 + 256 + tid], QEPS) / 127.0f;
    }
  }
  __syncthreads();

  i32x4 acc[2][8] = {};
  __builtin_amdgcn_s_setprio(1);
#pragma unroll
  for (int mt = 0; mt < 2; mt++) {
#pragma unroll
    for (int nt = 0; nt < 8; nt++) {
      i32x4 bfrag = *(const i32x4*)&u.K[nt * 16 + r16][quad * 16];
      acc[mt][nt] = __builtin_amdgcn_mfma_i32_16x16x64_i8(aq[mt], bfrag, acc[mt][nt], 0, 0, 0);
    }
  }
  __builtin_amdgcn_s_setprio(0);

  float skc[8], spc[8];
#pragma unroll
  for (int nt = 0; nt < 8; nt++) {
    skc[nt] = skv[nt * 16 + r16];
    spc[nt] = spv[nt * 16 + r16];
  }

  u32 pqh[2][4][2];
#pragma unroll
  for (int mt = 0; mt < 2; mt++) {
#pragma unroll
    for (int r = 0; r < 4; r++) {
      int row = rowbase + mt * 16 + quad * 4 + r;
      float sq = sqv[row];
      const u64* mrow = mb + ((size_t)b * NS + row) * 2;
      u64 m0 = mrow[0], m1 = mrow[1];
      float vals[8];
      float mx = -INFINITY;
#pragma unroll
      for (int nt = 0; nt < 8; nt++) {
        float v = (float)acc[mt][nt][r] * (sq * skc[nt]) * 0.125f;
        u64 bits = nt < 4 ? m0 : m1;
        if (((bits >> ((nt * 16 + r16) & 63)) & 1ull) == 0) v = -1e9f;
        vals[nt] = v;
        mx = fmaxf(mx, v);
      }
#pragma unroll
      for (int off = 1; off < 16; off <<= 1) mx = fmaxf(mx, __shfl_xor(mx, off));
      float sum = 0.0f;
#pragma unroll
      for (int nt = 0; nt < 8; nt++) { vals[nt] = __expf(vals[nt] - mx); sum += vals[nt]; }
#pragma unroll
      for (int off = 1; off < 16; off <<= 1) sum += __shfl_xor(sum, off);
#pragma unroll
      for (int nt = 0; nt < 4; nt++) {
        float p = vals[nt] / sum;
        float pq = fminf(fmaxf(rintf(p / spc[nt]), -128.f), 127.f);
        Ps[row][nt * 16 + r16] = f2bf(pq);
      }
#pragma unroll
      for (int n2 = 0; n2 < 2; n2++) {
        float pa_ = vals[4 + n2 * 2] / sum;
        float pb_ = vals[5 + n2 * 2] / sum;
        float qa = fminf(fmaxf(rintf(pa_ / spc[4 + n2 * 2]), -128.f), 127.f);
        float qb = fminf(fmaxf(rintf(pb_ / spc[5 + n2 * 2]), -128.f), 127.f);
        pqh[mt][r][n2] = (u32)f2bf(qa) | ((u32)f2bf(qb) << 16);
      }
    }
  }

  f32x4 xacc[2][4] = {};
#pragma unroll
  for (int half = 0; half < 2; half++) {
    __syncthreads();
    {
      int j = half * 64 + jl;
      float g = spv[j] * svv[j];
      int4 raw = half ? vpre1 : vpre0;
      const i8* rb = (const i8*)&raw;
#pragma unroll
      for (int d = 0; d < 16; d++) {
        float w = (float)rb[d] * g;
        u16 hi = f2bf(w);
        u.v.hi[d0v + d][jl] = hi;
        u.v.lo[d0v + d][jl] = f2bf(w - bf2f(hi));
      }
    }
    __syncthreads();
    __builtin_amdgcn_s_setprio(1);
#pragma unroll
    for (int kk = 0; kk < 2; kk++) {
      short8 pa[2];
#pragma unroll
      for (int mt = 0; mt < 2; mt++)
        pa[mt] = *(const short8*)&Ps[rowbase + mt * 16 + r16][kk * 32 + quad * 8];
#pragma unroll
      for (int nt = 0; nt < 4; nt++) {
        short8 vh = *(const short8*)&u.v.hi[nt * 16 + r16][kk * 32 + quad * 8];
        short8 vl = *(const short8*)&u.v.lo[nt * 16 + r16][kk * 32 + quad * 8];
#pragma unroll
        for (int mt = 0; mt < 2; mt++) {
          xacc[mt][nt] = __builtin_amdgcn_mfma_f32_16x16x32_bf16(pa[mt], vh, xacc[mt][nt], 0, 0, 0);
          xacc[mt][nt] = __builtin_amdgcn_mfma_f32_16x16x32_bf16(pa[mt], vl, xacc[mt][nt], 0, 0, 0);
        }
      }
    }
    __builtin_amdgcn_s_setprio(0);
    if (half == 0) {
#pragma unroll
      for (int mt = 0; mt < 2; mt++)
#pragma unroll
        for (int r = 0; r < 4; r++) {
          int row = rowbase + mt * 16 + quad * 4 + r;
#pragma unroll
          for (int n2 = 0; n2 < 2; n2++) {
            u32 pk = pqh[mt][r][n2];
            Ps[row][(n2 * 2) * 16 + r16] = (u16)(pk & 0xFFFFu);
            Ps[row][(n2 * 2 + 1) * 16 + r16] = (u16)(pk >> 16);
          }
        }
    }
  }

  float mx = -INFINITY;
#pragma unroll
  for (int mt = 0; mt < 2; mt++)
#pragma unroll
    for (int nt = 0; nt < 4; nt++)
#pragma unroll
      for (int r = 0; r < 4; r++) {
        int row = rowbase + mt * 16 + quad * 4 + r;
        xout[((size_t)b * NS + row) * NDM + h * NDK + nt * 16 + r16] = xacc[mt][nt][r];
        mx = fmaxf(mx, xacc[mt][nt][r]);
      }
#pragma unroll
  for (int off = 1; off < 64; off <<= 1) mx = fmaxf(mx, __shfl_xor(mx, off));
  if (lane == 0) xmw[wave] = mx;
  __syncthreads();
  if (tid == 0) {
    float m = fmaxf(fmaxf(xmw[0], xmw[1]), fmaxf(xmw[2], xmw[3]));
    atomicMax(xmax_slot, fenc(m));
  }
}

// ---------------- workspace layout ----------------
constexpr size_t OFF_SCL = 0;                                   // 8 KB (2048 u32)
constexpr size_t OFF_CS  = 8192;                                // colsum 4x1024 int = 16 KB
constexpr size_t OFF_MB  = OFF_CS + 4 * NDM * 4;                // mask bits 128 KB
constexpr size_t OFF_W   = OFF_MB + (size_t)NM * 16;            // i8 weights 4 MB
constexpr size_t OFF_XQ  = OFF_W + 4 * (size_t)NDM * NDM;       // i8 acts 3x8 MB
constexpr size_t OFF_PQ  = OFF_XQ + 3 * (size_t)NM * NDM;       // f32 proj 3x33.5 MB
constexpr size_t OFF_I8  = OFF_PQ + 3 * (size_t)NM * NDM * 4;   // attn i8 qkv 3x8 MB
constexpr size_t OFF_CM  = OFF_I8 + 3 * (size_t)NM * NDM;       // colmax scratch 512 KB
constexpr size_t OFF_RP  = OFF_CM + (size_t)NS * NB * NH * 4;   // rmax scratch 1.5 MB
// xout aliases projv (dead after qkv_i8); P never materialized

extern "C" void kernel_launch(void* const* d_in, const int* in_sizes, int n_in,
                              void* d_out, int out_size, void* d_ws, size_t ws_size,
                              hipStream_t stream) {
  const float* query = (const float*)d_in[0];
  const float* key = (const float*)d_in[1];
  const float* value = (const float*)d_in[2];
  const int* mask = (const int*)d_in[3];
  const float* Wq = (const float*)d_in[4]; const float* bq = (const float*)d_in[5];
  const float* Wk = (const float*)d_in[6]; const float* bk = (const float*)d_in[7];
  const float* Wv = (const float*)d_in[8]; const float* bv = (const float*)d_in[9];
  const float* Wo = (const float*)d_in[10]; const float* bo = (const float*)d_in[11];

  char* ws = (char*)d_ws;
  float* scl = (float*)(ws + OFF_SCL);
  u32* sclu = (u32*)scl;
  int* colsum = (int*)(ws + OFF_CS);
  u64* mb = (u64*)(ws + OFF_MB);
  i8* wb = (i8*)(ws + OFF_W);        // wq|wk|wv|wo
  i8* wob = wb + 3 * (size_t)NDM * NDM;
  i8* xq = (i8*)(ws + OFF_XQ);       // q|k|v shifted i8 (slot 0 reused for x)
  float* proj = (float*)(ws + OFF_PQ);
  i8* qkv8 = (i8*)(ws + OFF_I8);
  float* cm_part = (float*)(ws + OFF_CM);
  float* rmax_part = (float*)(ws + OFF_RP);
  float* xout = proj + 2 * (size_t)NM * NDM;
  i8* vi8 = qkv8 + 2 * (size_t)NM * NDM;

  maskbits_kernel<<<NM / 4, 256, 0, stream>>>(mask, mb, sclu);
  fused_max_kernel<<<dim3(512, 7), 256, 0, stream>>>(query, key, value, Wq, Wk, Wv, Wo, sclu);
  quant_w_i8_kernel<<<dim3(NDM, 4), 256, 0, stream>>>(Wq, Wk, Wv, Wo, wb, colsum, sclu);
  quant_a_kernel<<<dim3(512, 3), 256, 0, stream>>>(query, key, value, xq, sclu, 0);

  gemm_kernel<true><<<dim3(NM / BM, NDM / BN, 3), 256, 0, stream>>>(
      xq, wb, colsum, bq, bk, bv, proj, sclu, rmax_part);
  rmax_reduce_kernel<<<384, 256, 0, stream>>>(rmax_part, sclu);

  qkv_i8_kernel<<<dim3(512, 3), 256, 0, stream>>>(proj, qkv8, scl);

  // ---- attention: cooperative fused path with checked fallback ----
  static int coop_ok = -1;
  if (coop_ok < 0) {
    int nb = 0;
    hipError_t e = hipOccupancyMaxActiveBlocksPerMultiprocessor(&nb, attn_fused_kernel, 256, 0);
    coop_ok = (e == hipSuccess && nb >= 4) ? 1 : 0;  // need 1024 co-resident (256 CU x 4)
  }
  bool launched = false;
  if (coop_ok) {
    const i8* a_q = qkv8;
    const i8* a_k = qkv8 + (size_t)NM * NDM;
    const i8* a_v = vi8;
    const u64* a_mb = mb;
    const float* a_scl = scl;
    u32* a_sclu = sclu;
    float* a_cm = cm_part;
    float* a_xout = xout;
    u32* a_xm = sclu + 7;
    void* args[] = {&a_q, &a_k, &a_v, &a_mb, &a_scl, &a_sclu, &a_cm, &a_xout, &a_xm};
    hipError_t e = hipLaunchCooperativeKernel((const void*)attn_fused_kernel,
                                              dim3(NB * NH), dim3(256), args, 0, stream);
    launched = (e == hipSuccess);
    if (!launched) coop_ok = 0;
  }
  if (!launched) {
    attn_colmax_kernel<<<NB * NH, 256, 0, stream>>>(qkv8, qkv8 + (size_t)NM * NDM, mb, scl,
                                                    cm_part);
    colmax_reduce_kernel<<<NS, 256, 0, stream>>>(cm_part, sclu);
    attn_pv2_kernel<<<NB * NH, 256, 0, stream>>>(qkv8, qkv8 + (size_t)NM * NDM, vi8, mb,
                                                 scl, xout, sclu + 7);
  }

  quant_a_kernel<<<dim3(512, 1), 256, 0, stream>>>(xout, xout, xout, xq, sclu, 7);
  gemm_kernel<false><<<dim3(NM / BM, NDM / BN, 1), 256, 0, stream>>>(
      xq, wob, colsum, bo, bo, bo, (float*)d_out, sclu, rmax_part);
}

// Round 13
// 384.584 us; speedup vs baseline: 1.0164x; 1.0005x over previous
//
#include <hip/hip_runtime.h>
#include <hip/hip_bf16.h>
#include <math.h>

typedef unsigned short u16;
typedef unsigned int u32;
typedef unsigned long long u64;
typedef signed char i8;

constexpr int NB = 64, NS = 128, NDM = 1024, NH = 16, NDK = 64;
constexpr int NM = NB * NS;  // 8192
constexpr float QEPS = 1e-8f;

typedef __attribute__((ext_vector_type(8))) short short8;
typedef __attribute__((ext_vector_type(4))) float f32x4;
typedef __attribute__((ext_vector_type(4))) int i32x4;

__device__ __forceinline__ u32 fenc(float f) {
  u32 u = __float_as_uint(f);
  return (u & 0x80000000u) ? ~u : (u | 0x80000000u);
}
__device__ __forceinline__ float fdec(u32 u) {
  u = (u & 0x80000000u) ? (u & 0x7FFFFFFFu) : ~u;
  return __uint_as_float(u);
}
// quantized values are small integers -> exact bf16 truncation
__device__ __forceinline__ u16 f2bf(float f) { return (u16)(__float_as_uint(f) >> 16); }
__device__ __forceinline__ float bf2f(u16 u) { return __uint_as_float(((u32)u) << 16); }

// async global->LDS, 16B per lane; lds dest = wave-uniform base + lane*16
__device__ __forceinline__ void glds16(const void* g, void* l) {
  __builtin_amdgcn_global_load_lds(
      (const __attribute__((address_space(1))) void*)(unsigned long long)(uintptr_t)g,
      (__attribute__((address_space(3))) void*)(u32)(uintptr_t)l, 16, 0, 0);
}

// ---- scale slots (u32/float at ws offset 0) ----
// [0..2] enc max(q,k,v)  [3..6] enc absmax(W*)  [7] enc max(x)
// [8..135] absmax_q per s; [136..263] absmax_k; [264..391] absmax_v (plain float bits)
// [392..519] colmax_p per j (plain float bits)

// mask[B,S,S] int32 -> bitmask [B*S][2] u64; block 0 also zeroes the scale slots
__global__ void maskbits_kernel(const int* __restrict__ mask, u64* __restrict__ mb,
                                u32* __restrict__ scl) {
  if (blockIdx.x == 0) {
    for (int i = threadIdx.x; i < 2048; i += blockDim.x) scl[i] = 0u;
  }
  int row = blockIdx.x * 4 + (threadIdx.x >> 6);
  int lane = threadIdx.x & 63;
  const int* mrow = mask + (size_t)row * NS;
  u64 b0 = __ballot(mrow[lane] != 0);
  u64 b1 = __ballot(mrow[64 + lane] != 0);
  if (lane == 0) { mb[row * 2] = b0; mb[row * 2 + 1] = b1; }
}

// fused 7-way max reduce: y=0..2 max(q,k,v); y=3..6 absmax(Wq..Wo)
__global__ void fused_max_kernel(const float* __restrict__ q, const float* __restrict__ k,
                                 const float* __restrict__ v, const float* __restrict__ w0,
                                 const float* __restrict__ w1, const float* __restrict__ w2,
                                 const float* __restrict__ w3, u32* __restrict__ sclu) {
  int y = blockIdx.y;
  const float* src; size_t n4; int ab;
  switch (y) {
    case 0: src = q; n4 = (size_t)NM * NDM / 4; ab = 0; break;
    case 1: src = k; n4 = (size_t)NM * NDM / 4; ab = 0; break;
    case 2: src = v; n4 = (size_t)NM * NDM / 4; ab = 0; break;
    case 3: src = w0; n4 = (size_t)NDM * NDM / 4; ab = 1; break;
    case 4: src = w1; n4 = (size_t)NDM * NDM / 4; ab = 1; break;
    case 5: src = w2; n4 = (size_t)NDM * NDM / 4; ab = 1; break;
    default: src = w3; n4 = (size_t)NDM * NDM / 4; ab = 1; break;
  }
  float m = -INFINITY;
  size_t stride = (size_t)gridDim.x * blockDim.x;
  for (size_t i = (size_t)blockIdx.x * blockDim.x + threadIdx.x; i < n4; i += stride) {
    float4 f = ((const float4*)src)[i];
    if (ab) { f.x = fabsf(f.x); f.y = fabsf(f.y); f.z = fabsf(f.z); f.w = fabsf(f.w); }
    m = fmaxf(m, fmaxf(fmaxf(f.x, f.y), fmaxf(f.z, f.w)));
  }
  for (int off = 32; off; off >>= 1) m = fmaxf(m, __shfl_down(m, off));
  __shared__ float sm[4];
  if ((threadIdx.x & 63) == 0) sm[threadIdx.x >> 6] = m;
  __syncthreads();
  if (threadIdx.x == 0) {
    float r = fmaxf(fmaxf(sm[0], sm[1]), fmaxf(sm[2], sm[3]));
    atomicMax(&sclu[y], fenc(r));
  }
}

// weight quant -> i8 (-127..127) + per-output-channel column sums (for u8 shift fix)
__global__ __launch_bounds__(256)
void quant_w_i8_kernel(const float* __restrict__ w0, const float* __restrict__ w1,
                       const float* __restrict__ w2, const float* __restrict__ w3,
                       i8* __restrict__ dst, int* __restrict__ colsum,
                       const u32* __restrict__ sclu) {
  int y = blockIdx.y, row = blockIdx.x, tid = threadIdx.x;
  const float* src = (y == 0 ? w0 : y == 1 ? w1 : y == 2 ? w2 : w3) + (size_t)row * NDM;
  float s = fmaxf(fdec(sclu[3 + y]), QEPS) / 127.0f;
  float4 f = ((const float4*)src)[tid];
  int a = (int)fminf(fmaxf(rintf(f.x / s), -127.f), 127.f);
  int b = (int)fminf(fmaxf(rintf(f.y / s), -127.f), 127.f);
  int c = (int)fminf(fmaxf(rintf(f.z / s), -127.f), 127.f);
  int d = (int)fminf(fmaxf(rintf(f.w / s), -127.f), 127.f);
  ((int*)(dst + (size_t)y * NDM * NDM + (size_t)row * NDM))[tid] =
      (a & 255) | ((b & 255) << 8) | ((c & 255) << 16) | ((d & 255) << 24);
  int ssum = a + b + c + d;
  for (int off = 32; off; off >>= 1) ssum += __shfl_down(ssum, off);
  __shared__ int sm[4];
  if ((tid & 63) == 0) sm[tid >> 6] = ssum;
  __syncthreads();
  if (tid == 0) colsum[y * NDM + row] = sm[0] + sm[1] + sm[2] + sm[3];
}

// uint8 activation fake-quant -> shifted i8 (q-128); y selects source/slot/dst
__global__ void quant_a_kernel(const float* __restrict__ s0, const float* __restrict__ s1,
                               const float* __restrict__ s2, i8* __restrict__ dst,
                               const u32* __restrict__ sclu, int slot_base) {
  int y = blockIdx.y;
  const float* src = y == 0 ? s0 : y == 1 ? s1 : s2;
  i8* d = dst + (size_t)y * NM * NDM;
  float s = fmaxf(fdec(sclu[slot_base + y]), QEPS) / 255.0f;
  size_t n4 = (size_t)NM * NDM / 4;
  size_t stride = (size_t)gridDim.x * blockDim.x;
  for (size_t i = (size_t)blockIdx.x * blockDim.x + threadIdx.x; i < n4; i += stride) {
    float4 f = ((const float4*)src)[i];
    int a = (int)fminf(fmaxf(rintf(f.x / s), 0.f), 255.f) - 128;
    int b = (int)fminf(fmaxf(rintf(f.y / s), 0.f), 255.f) - 128;
    int c = (int)fminf(fmaxf(rintf(f.z / s), 0.f), 255.f) - 128;
    int e = (int)fminf(fmaxf(rintf(f.w / s), 0.f), 255.f) - 128;
    ((int*)d)[i] = (a & 255) | ((b & 255) << 8) | ((c & 255) << 16) | ((e & 255) << 24);
  }
}

// proj fp32 -> int8 with per-s scale; y=0..2 selects q/k/v
__global__ void qkv_i8_kernel(const float* __restrict__ projbase, i8* __restrict__ dstbase,
                              const float* __restrict__ scl) {
  int y = blockIdx.y;
  const float* src = projbase + (size_t)y * NM * NDM;
  i8* dst = dstbase + (size_t)y * NM * NDM;
  const float* sb = scl + 8 + y * 128;
  size_t n4 = (size_t)NM * NDM / 4;
  size_t stride = (size_t)gridDim.x * blockDim.x;
  for (size_t i = (size_t)blockIdx.x * blockDim.x + threadIdx.x; i < n4; i += stride) {
    int s_idx = (int)((i >> 8) & 127);
    float s = fmaxf(sb[s_idx], QEPS) / 127.0f;
    float4 f = ((const float4*)src)[i];
    int a = (int)fminf(fmaxf(rintf(f.x / s), -128.f), 127.f);
    int b = (int)fminf(fmaxf(rintf(f.y / s), -128.f), 127.f);
    int c = (int)fminf(fmaxf(rintf(f.z / s), -128.f), 127.f);
    int d = (int)fminf(fmaxf(rintf(f.w / s), -128.f), 127.f);
    ((int*)dst)[i] = (a & 255) | ((b & 255) << 8) | ((c & 255) << 16) | ((d & 255) << 24);
  }
}

// ---------------- GEMM: i8 MFMA, dbuf glds16, 64x32 wave tile ----------------
constexpr int BM = 128, BN = 64, BK = 64, KTILES = NDM / BK;

template <bool PROJ>
__global__ __launch_bounds__(256, 4)
void gemm_kernel(const i8* __restrict__ Abase, const i8* __restrict__ Wbase,
                 const int* __restrict__ colsum, const float* __restrict__ b0,
                 const float* __restrict__ b1, const float* __restrict__ b2,
                 float* __restrict__ Cbase, u32* __restrict__ sclu,
                 float* __restrict__ rmax_part) {
  constexpr int K = NDM, N = NDM;
  const int z = PROJ ? blockIdx.z : 0;
  const i8* A = Abase + (size_t)z * NM * NDM;
  const i8* Wt = PROJ ? (Wbase + (size_t)z * NDM * NDM) : Wbase;
  const float* bias = PROJ ? (z == 0 ? b0 : z == 1 ? b1 : b2) : b0;
  float* C = PROJ ? (Cbase + (size_t)z * NM * NDM) : Cbase;
  const u32* slot_in = PROJ ? (sclu + z) : (sclu + 7);
  const u32* slot_w = PROJ ? (sclu + 3 + z) : (sclu + 6);
  const int* cs = colsum + (PROJ ? z : 3) * NDM;

  __shared__ __align__(16) i8 As[2][BM][BK];  // 16 KB (dbuf)
  __shared__ __align__(16) i8 Bs[2][BN][BK];  // 8 KB (dbuf)
  __shared__ float rmax2[4][64];

  const int tid = threadIdx.x;
  const int lane = tid & 63, wave = tid >> 6;
  const int wm = (wave & 1) * 64, wn = (wave >> 1) * 32;
  const int r16 = lane & 15, quad = lane >> 4;
  const int bm = blockIdx.x * BM, bn = blockIdx.y * BN;

  const int lrow = lane >> 2, lcol = (lane & 3) * 16;  // 16 rows per glds16, 64B rows
  const i8* Ab = A + (size_t)(bm + wave * 32 + lrow) * K + lcol;
  const i8* Bb = Wt + (size_t)(bn + wave * 16 + lrow) * K + lcol;

  i32x4 acc[4][2] = {};

  // prologue: stage tile 0
  glds16(Ab, &As[0][wave * 32][0]);
  glds16(Ab + (size_t)16 * K, &As[0][wave * 32 + 16][0]);
  glds16(Bb, &Bs[0][wave * 16][0]);
  __syncthreads();

  int cur = 0;
  for (int t = 0; t < KTILES; t++) {
    if (t + 1 < KTILES) {  // issue next tile's loads BEFORE computing current
      int k0 = (t + 1) * BK;
      glds16(Ab + k0, &As[cur ^ 1][wave * 32][0]);
      glds16(Ab + (size_t)16 * K + k0, &As[cur ^ 1][wave * 32 + 16][0]);
      glds16(Bb + k0, &Bs[cur ^ 1][wave * 16][0]);
    }
    i32x4 af[4], bfr[2];
#pragma unroll
    for (int i = 0; i < 4; i++)
      af[i] = *(const i32x4*)(&As[cur][wm + i * 16 + r16][quad * 16]);
#pragma unroll
    for (int j = 0; j < 2; j++)
      bfr[j] = *(const i32x4*)(&Bs[cur][wn + j * 16 + r16][quad * 16]);
#pragma unroll
    for (int i = 0; i < 4; i++)
#pragma unroll
      for (int j = 0; j < 2; j++)
        acc[i][j] = __builtin_amdgcn_mfma_i32_16x16x64_i8(af[i], bfr[j], acc[i][j], 0, 0, 0);
    __syncthreads();  // drains this iter's prefetch (vmcnt0) + fences buffer reuse
    cur ^= 1;
  }

  float s_in = fmaxf(fdec(*slot_in), QEPS) / 255.0f;
  float s_w = fmaxf(fdec(*slot_w), QEPS) / 127.0f;
  float sc = s_in * s_w;

  float bq[2];
  int csj[2];
#pragma unroll
  for (int j = 0; j < 2; j++) {
    int gc = bn + wn + j * 16 + r16;
    bq[j] = rintf(bias[gc] / sc) * sc;
    csj[j] = cs[gc] << 7;  // +128 * colsum(W): undoes the x-128 input shift
  }
#pragma unroll
  for (int i = 0; i < 4; i++) {
#pragma unroll
    for (int r = 0; r < 4; r++) {
      int l64 = i * 16 + quad * 4 + r;  // 0..63 within wave-M group
      int gr = bm + wm + l64;
      float rm = 0.0f;
#pragma unroll
      for (int j = 0; j < 2; j++) {
        int gc = bn + wn + j * 16 + r16;
        float val = (float)(acc[i][j][r] + csj[j]) * sc + bq[j];
        C[(size_t)gr * N + gc] = val;
        if (PROJ) rm = fmaxf(rm, fabsf(val));
      }
      if (PROJ) {
#pragma unroll
        for (int off = 1; off < 16; off <<= 1) rm = fmaxf(rm, __shfl_xor(rm, off));
        if (r16 == 0) rmax2[wave][l64] = rm;
      }
    }
  }
  if (PROJ) {
    // per-block rowmax vector -> scratch (coalesced store; NO atomics)
    __syncthreads();
    if (tid < BM) {
      int g = tid >> 6, l = tid & 63;  // waves {g, g+2} share wm group g
      float m = fmaxf(rmax2[g][l], rmax2[g + 2][l]);
      int blockId = z * 1024 + blockIdx.x * 16 + blockIdx.y;
      rmax_part[(size_t)blockId * 128 + tid] = m;
    }
  }
}

// rmax_part[z*1024 + b][lr] -> scl[8 + z*128 + lr] = max over b
__global__ void rmax_reduce_kernel(const float* __restrict__ part, u32* __restrict__ sclu) {
  int slot = blockIdx.x;  // 0..383
  int z = slot >> 7, lr = slot & 127;
  const float* base = part + (size_t)z * 1024 * 128 + lr;
  float m = 0.0f;
  for (int i = threadIdx.x; i < 1024; i += blockDim.x) m = fmaxf(m, base[(size_t)i * 128]);
  for (int off = 32; off; off >>= 1) m = fmaxf(m, __shfl_down(m, off));
  __shared__ float sm[4];
  if ((threadIdx.x & 63) == 0) sm[threadIdx.x >> 6] = m;
  __syncthreads();
  if (threadIdx.x == 0)
    sclu[8 + slot] = __float_as_uint(fmaxf(fmaxf(sm[0], sm[1]), fmaxf(sm[2], sm[3])));
}

// ---------------- attention ----------------
// Phase 1: QK^T + softmax; per-block colmax vector -> scratch.
// Occupancy-tuned (same treatment pv2 got in r2/r5): Q frags -> registers,
// K via glds16 packed [NS][64], mask bits staged in LDS, launch_bounds(256,4).
// LDS 23.5 KB -> ~13 KB.
__global__ __launch_bounds__(256, 4)
void attn_colmax_kernel(const i8* __restrict__ qi8, const i8* __restrict__ ki8,
                        const u64* __restrict__ mb, const float* __restrict__ scl,
                        float* __restrict__ cm_part) {
  const int bh = blockIdx.x, b = bh >> 4, h = bh & 15;
  const int tid = threadIdx.x, lane = tid & 63, wave = tid >> 6;
  const int r16 = lane & 15, quad = lane >> 4;
  const int rowbase = wave * 32;

  __shared__ __align__(16) i8 Ks[NS][64];   // 8 KB (glds16 dest)
  __shared__ u64 mbs[NS][2];                // 2 KB
  __shared__ float sqv[NS], skv[NS];
  __shared__ float cmw[4][NS];

  i32x4 aq[2];
  {
    const i8* qp = qi8 + (size_t)b * NS * NDM + h * NDK;
#pragma unroll
    for (int mt = 0; mt < 2; mt++)
      aq[mt] = *(const i32x4*)(qp + (size_t)(rowbase + mt * 16 + r16) * NDM + quad * 16);
    const int lrow = lane >> 2, lcol = (lane & 3) * 16;
#pragma unroll
    for (int p = 0; p < 2; p++) {
      int r = wave * 32 + p * 16;
      glds16(ki8 + (size_t)(b * NS + r + lrow) * NDM + h * NDK + lcol, &Ks[r][0]);
    }
    mbs[tid >> 1][tid & 1] = mb[((size_t)b * NS + (tid >> 1)) * 2 + (tid & 1)];
    if (tid < NS) {
      sqv[tid] = fmaxf(scl[8 + tid], QEPS) / 127.0f;
      skv[tid] = fmaxf(scl[8 + 128 + tid], QEPS) / 127.0f;
    }
  }
  __syncthreads();

  i32x4 acc[2][8] = {};
  __builtin_amdgcn_s_setprio(1);
#pragma unroll
  for (int mt = 0; mt < 2; mt++) {
#pragma unroll
    for (int nt = 0; nt < 8; nt++) {
      i32x4 bfrag = *(const i32x4*)&Ks[nt * 16 + r16][quad * 16];
      acc[mt][nt] = __builtin_amdgcn_mfma_i32_16x16x64_i8(aq[mt], bfrag, acc[mt][nt], 0, 0, 0);
    }
  }
  __builtin_amdgcn_s_setprio(0);

  float skc[8], cm[8];
#pragma unroll
  for (int nt = 0; nt < 8; nt++) { skc[nt] = skv[nt * 16 + r16]; cm[nt] = 0.0f; }

#pragma unroll
  for (int mt = 0; mt < 2; mt++) {
#pragma unroll
    for (int r = 0; r < 4; r++) {
      int row = rowbase + mt * 16 + quad * 4 + r;
      float sq = sqv[row];
      u64 m0 = mbs[row][0], m1 = mbs[row][1];
      float vals[8];
      float mx = -INFINITY;
#pragma unroll
      for (int nt = 0; nt < 8; nt++) {
        float v = (float)acc[mt][nt][r] * (sq * skc[nt]) * 0.125f;
        u64 bits = nt < 4 ? m0 : m1;
        if (((bits >> ((nt * 16 + r16) & 63)) & 1ull) == 0) v = -1e9f;
        vals[nt] = v;
        mx = fmaxf(mx, v);
      }
#pragma unroll
      for (int off = 1; off < 16; off <<= 1) mx = fmaxf(mx, __shfl_xor(mx, off));
      float sum = 0.0f;
#pragma unroll
      for (int nt = 0; nt < 8; nt++) { vals[nt] = __expf(vals[nt] - mx); sum += vals[nt]; }
#pragma unroll
      for (int off = 1; off < 16; off <<= 1) sum += __shfl_xor(sum, off);
#pragma unroll
      for (int nt = 0; nt < 8; nt++) {
        float p = vals[nt] / sum;
        cm[nt] = fmaxf(cm[nt], p);
      }
    }
  }

#pragma unroll
  for (int nt = 0; nt < 8; nt++) {
    float c = cm[nt];
    c = fmaxf(c, __shfl_xor(c, 16));
    c = fmaxf(c, __shfl_xor(c, 32));
    if (quad == 0) cmw[wave][nt * 16 + r16] = c;
  }
  __syncthreads();
  if (tid < NS) {
    float c = fmaxf(fmaxf(cmw[0][tid], cmw[1][tid]), fmaxf(cmw[2][tid], cmw[3][tid]));
    cm_part[(size_t)tid * (NB * NH) + bh] = c;  // [j][bh] layout, plain store
  }
}

// cm_part[j][0..1023] -> scl[392+j] = max (identical value set as atomics would give)
__global__ void colmax_reduce_kernel(const float* __restrict__ cm_part,
                                     u32* __restrict__ sclu) {
  int j = blockIdx.x;
  const float* row = cm_part + (size_t)j * (NB * NH);
  float m = 0.0f;
  for (int i = threadIdx.x; i < NB * NH; i += blockDim.x) m = fmaxf(m, row[i]);
  for (int off = 32; off; off >>= 1) m = fmaxf(m, __shfl_down(m, off));
  __shared__ float sm[4];
  if ((threadIdx.x & 63) == 0) sm[threadIdx.x >> 6] = m;
  __syncthreads();
  if (threadIdx.x == 0)
    sclu[392 + j] = __float_as_uint(fmaxf(fmaxf(sm[0], sm[1]), fmaxf(sm[2], sm[3])));
}

// Phase 2: recompute QK^T + softmax (bitwise-identical to phase 1), quantize P with
// final colmax scales into LDS (one 64-col half at a time), then PV.
// V prefetched to regs at entry (T14), K staged via global_load_lds, mask bits in
// LDS (union slack), setprio around MFMA, ONE xmax atomic per block.
__global__ __launch_bounds__(256, 4)
void attn_pv2_kernel(const i8* __restrict__ qi8, const i8* __restrict__ ki8,
                     const i8* __restrict__ vi8, const u64* __restrict__ mb,
                     const float* __restrict__ scl, float* __restrict__ xout,
                     u32* __restrict__ xmax_slot) {
  const int bh = blockIdx.x, b = bh >> 4, h = bh & 15;
  const int tid = threadIdx.x, lane = tid & 63, wave = tid >> 6;
  const int r16 = lane & 15, quad = lane >> 4;
  const int rowbase = wave * 32;

  union SU {
    struct { i8 K[NS][64]; u64 mbs[NS][2]; } qk;    // 10 KB (QK^T+softmax phase)
    struct { u16 hi[64][72]; u16 lo[64][72]; } v;   // 18.4 KB (PV phase)
  };
  __shared__ __align__(16) SU u;
  __shared__ __align__(16) u16 Ps[NS][72];  // 18 KB; holds one 64-col half at a time
  __shared__ float sqv[NS], skv[NS], spv[NS], svv[NS];
  __shared__ float xmw[4];

  // --- issue ALL global loads up front: V (both halves), Q frags, K via glds16 ---
  const int jl = tid >> 2, d0v = (tid & 3) * 16;
  const i8* vb = vi8 + (size_t)(b * NS + jl) * NDM + h * NDK + d0v;
  int4 vpre0 = *(const int4*)vb;                        // V rows 0..63
  int4 vpre1 = *(const int4*)(vb + (size_t)64 * NDM);   // V rows 64..127

  i32x4 aq[2];
  {
    const i8* qp = qi8 + (size_t)b * NS * NDM + h * NDK;
#pragma unroll
    for (int mt = 0; mt < 2; mt++)
      aq[mt] = *(const i32x4*)(qp + (size_t)(rowbase + mt * 16 + r16) * NDM + quad * 16);
    const int lrow = lane >> 2, lcol = (lane & 3) * 16;
#pragma unroll
    for (int p = 0; p < 2; p++) {
      int r = wave * 32 + p * 16;
      glds16(ki8 + (size_t)(b * NS + r + lrow) * NDM + h * NDK + lcol, &u.qk.K[r][0]);
    }
    u.qk.mbs[tid >> 1][tid & 1] = mb[((size_t)b * NS + (tid >> 1)) * 2 + (tid & 1)];
    if (tid < NS) {
      sqv[tid] = fmaxf(scl[8 + tid], QEPS) / 127.0f;
      skv[tid] = fmaxf(scl[8 + 128 + tid], QEPS) / 127.0f;
      spv[tid] = fmaxf(scl[392 + tid], QEPS) / 127.0f;
      svv[tid] = fmaxf(scl[8 + 256 + tid], QEPS) / 127.0f;
    }
  }
  __syncthreads();

  i32x4 acc[2][8] = {};
  __builtin_amdgcn_s_setprio(1);
#pragma unroll
  for (int mt = 0; mt < 2; mt++) {
#pragma unroll
    for (int nt = 0; nt < 8; nt++) {
      i32x4 bfrag = *(const i32x4*)&u.qk.K[nt * 16 + r16][quad * 16];
      acc[mt][nt] = __builtin_amdgcn_mfma_i32_16x16x64_i8(aq[mt], bfrag, acc[mt][nt], 0, 0, 0);
    }
  }
  __builtin_amdgcn_s_setprio(0);

  float skc[8], spc[8];
#pragma unroll
  for (int nt = 0; nt < 8; nt++) {
    skc[nt] = skv[nt * 16 + r16];
    spc[nt] = spv[nt * 16 + r16];
  }

  // Softmax (bitwise-identical to phase 1). Low half (cols 0-63) -> Ps now;
  // high half (cols 64-127) -> packed bf16 in registers, written after PV half 0.
  // Ps is wave-local (each wave touches only its own 32 rows), so no barrier needed.
  u32 pqh[2][4][2];
#pragma unroll
  for (int mt = 0; mt < 2; mt++) {
#pragma unroll
    for (int r = 0; r < 4; r++) {
      int row = rowbase + mt * 16 + quad * 4 + r;
      float sq = sqv[row];
      u64 m0 = u.qk.mbs[row][0], m1 = u.qk.mbs[row][1];
      float vals[8];
      float mx = -INFINITY;
#pragma unroll
      for (int nt = 0; nt < 8; nt++) {
        float v = (float)acc[mt][nt][r] * (sq * skc[nt]) * 0.125f;
        u64 bits = nt < 4 ? m0 : m1;
        if (((bits >> ((nt * 16 + r16) & 63)) & 1ull) == 0) v = -1e9f;
        vals[nt] = v;
        mx = fmaxf(mx, v);
      }
#pragma unroll
      for (int off = 1; off < 16; off <<= 1) mx = fmaxf(mx, __shfl_xor(mx, off));
      float sum = 0.0f;
#pragma unroll
      for (int nt = 0; nt < 8; nt++) { vals[nt] = __expf(vals[nt] - mx); sum += vals[nt]; }
#pragma unroll
      for (int off = 1; off < 16; off <<= 1) sum += __shfl_xor(sum, off);
#pragma unroll
      for (int nt = 0; nt < 4; nt++) {
        float p = vals[nt] / sum;  // bitwise equal to phase-1 p
        float pq = fminf(fmaxf(rintf(p / spc[nt]), -128.f), 127.f);
        Ps[row][nt * 16 + r16] = f2bf(pq);  // small ints: exact in bf16
      }
#pragma unroll
      for (int n2 = 0; n2 < 2; n2++) {
        float pa_ = vals[4 + n2 * 2] / sum;
        float pb_ = vals[5 + n2 * 2] / sum;
        float qa = fminf(fmaxf(rintf(pa_ / spc[4 + n2 * 2]), -128.f), 127.f);
        float qb = fminf(fmaxf(rintf(pb_ / spc[5 + n2 * 2]), -128.f), 127.f);
        pqh[mt][r][n2] = (u32)f2bf(qa) | ((u32)f2bf(qb) << 16);
      }
    }
  }

  f32x4 xacc[2][4] = {};
#pragma unroll
  for (int half = 0; half < 2; half++) {
    __syncthreads();  // half0: all waves done with u.qk (K+mbs); half1: V half0 reads done
    {
      int j = half * 64 + jl;
      float g = spv[j] * svv[j];
      int4 raw = half ? vpre1 : vpre0;  // prefetched at entry; latency already hidden
      const i8* rb = (const i8*)&raw;
#pragma unroll
      for (int d = 0; d < 16; d++) {
        float w = (float)rb[d] * g;
        u16 hi = f2bf(w);
        u.v.hi[d0v + d][jl] = hi;
        u.v.lo[d0v + d][jl] = f2bf(w - bf2f(hi));
      }
    }
    __syncthreads();
    __builtin_amdgcn_s_setprio(1);
#pragma unroll
    for (int kk = 0; kk < 2; kk++) {
      short8 pa[2];
#pragma unroll
      for (int mt = 0; mt < 2; mt++)
        pa[mt] = *(const short8*)&Ps[rowbase + mt * 16 + r16][kk * 32 + quad * 8];
#pragma unroll
      for (int nt = 0; nt < 4; nt++) {
        short8 vh = *(const short8*)&u.v.hi[nt * 16 + r16][kk * 32 + quad * 8];
        short8 vl = *(const short8*)&u.v.lo[nt * 16 + r16][kk * 32 + quad * 8];
#pragma unroll
        for (int mt = 0; mt < 2; mt++) {
          xacc[mt][nt] = __builtin_amdgcn_mfma_f32_16x16x32_bf16(pa[mt], vh, xacc[mt][nt], 0, 0, 0);
          xacc[mt][nt] = __builtin_amdgcn_mfma_f32_16x16x32_bf16(pa[mt], vl, xacc[mt][nt], 0, 0, 0);
        }
      }
    }
    __builtin_amdgcn_s_setprio(0);
    if (half == 0) {
      // Overwrite Ps with cols 64-127 (wave-local rows; own reads above are done
      // in program order, other waves never touch these rows).
#pragma unroll
      for (int mt = 0; mt < 2; mt++)
#pragma unroll
        for (int r = 0; r < 4; r++) {
          int row = rowbase + mt * 16 + quad * 4 + r;
#pragma unroll
          for (int n2 = 0; n2 < 2; n2++) {
            u32 pk = pqh[mt][r][n2];
            Ps[row][(n2 * 2) * 16 + r16] = (u16)(pk & 0xFFFFu);
            Ps[row][(n2 * 2 + 1) * 16 + r16] = (u16)(pk >> 16);
          }
        }
    }
  }

  float mx = -INFINITY;
#pragma unroll
  for (int mt = 0; mt < 2; mt++)
#pragma unroll
    for (int nt = 0; nt < 4; nt++)
#pragma unroll
      for (int r = 0; r < 4; r++) {
        int row = rowbase + mt * 16 + quad * 4 + r;
        xout[((size_t)b * NS + row) * NDM + h * NDK + nt * 16 + r16] = xacc[mt][nt][r];
        mx = fmaxf(mx, xacc[mt][nt][r]);
      }
#pragma unroll
  for (int off = 1; off < 64; off <<= 1) mx = fmaxf(mx, __shfl_xor(mx, off));
  if (lane == 0) xmw[wave] = mx;
  __syncthreads();
  if (tid == 0) {
    float m = fmaxf(fmaxf(xmw[0], xmw[1]), fmaxf(xmw[2], xmw[3]));
    atomicMax(xmax_slot, fenc(m));  // 1 atomic/block
  }
}

// ---------------- workspace layout ----------------
constexpr size_t OFF_SCL = 0;                                   // 8 KB (2048 u32)
constexpr size_t OFF_CS  = 8192;                                // colsum 4x1024 int = 16 KB
constexpr size_t OFF_MB  = OFF_CS + 4 * NDM * 4;                // mask bits 128 KB
constexpr size_t OFF_W   = OFF_MB + (size_t)NM * 16;            // i8 weights 4 MB
constexpr size_t OFF_XQ  = OFF_W + 4 * (size_t)NDM * NDM;       // i8 acts 3x8 MB
constexpr size_t OFF_PQ  = OFF_XQ + 3 * (size_t)NM * NDM;       // f32 proj 3x33.5 MB
constexpr size_t OFF_I8  = OFF_PQ + 3 * (size_t)NM * NDM * 4;   // attn i8 qkv 3x8 MB
constexpr size_t OFF_CM  = OFF_I8 + 3 * (size_t)NM * NDM;       // colmax scratch 512 KB
constexpr size_t OFF_RP  = OFF_CM + (size_t)NS * NB * NH * 4;   // rmax scratch 1.5 MB
// xout aliases projv (dead after qkv_i8); P is never materialized (flash recompute)

extern "C" void kernel_launch(void* const* d_in, const int* in_sizes, int n_in,
                              void* d_out, int out_size, void* d_ws, size_t ws_size,
                              hipStream_t stream) {
  const float* query = (const float*)d_in[0];
  const float* key = (const float*)d_in[1];
  const float* value = (const float*)d_in[2];
  const int* mask = (const int*)d_in[3];
  const float* Wq = (const float*)d_in[4]; const float* bq = (const float*)d_in[5];
  const float* Wk = (const float*)d_in[6]; const float* bk = (const float*)d_in[7];
  const float* Wv = (const float*)d_in[8]; const float* bv = (const float*)d_in[9];
  const float* Wo = (const float*)d_in[10]; const float* bo = (const float*)d_in[11];

  char* ws = (char*)d_ws;
  float* scl = (float*)(ws + OFF_SCL);
  u32* sclu = (u32*)scl;
  int* colsum = (int*)(ws + OFF_CS);
  u64* mb = (u64*)(ws + OFF_MB);
  i8* wb = (i8*)(ws + OFF_W);        // wq|wk|wv|wo
  i8* wob = wb + 3 * (size_t)NDM * NDM;
  i8* xq = (i8*)(ws + OFF_XQ);       // q|k|v shifted i8 (slot 0 reused for x)
  float* proj = (float*)(ws + OFF_PQ);
  i8* qkv8 = (i8*)(ws + OFF_I8);
  float* cm_part = (float*)(ws + OFF_CM);
  float* rmax_part = (float*)(ws + OFF_RP);
  float* xout = proj + 2 * (size_t)NM * NDM;
  i8* vi8 = qkv8 + 2 * (size_t)NM * NDM;

  maskbits_kernel<<<NM / 4, 256, 0, stream>>>(mask, mb, sclu);
  fused_max_kernel<<<dim3(512, 7), 256, 0, stream>>>(query, key, value, Wq, Wk, Wv, Wo, sclu);
  quant_w_i8_kernel<<<dim3(NDM, 4), 256, 0, stream>>>(Wq, Wk, Wv, Wo, wb, colsum, sclu);
  quant_a_kernel<<<dim3(512, 3), 256, 0, stream>>>(query, key, value, xq, sclu, 0);

  gemm_kernel<true><<<dim3(NM / BM, NDM / BN, 3), 256, 0, stream>>>(
      xq, wb, colsum, bq, bk, bv, proj, sclu, rmax_part);
  rmax_reduce_kernel<<<384, 256, 0, stream>>>(rmax_part, sclu);

  qkv_i8_kernel<<<dim3(512, 3), 256, 0, stream>>>(proj, qkv8, scl);

  attn_colmax_kernel<<<NB * NH, 256, 0, stream>>>(qkv8, qkv8 + (size_t)NM * NDM, mb, scl,
                                                  cm_part);
  colmax_reduce_kernel<<<NS, 256, 0, stream>>>(cm_part, sclu);
  attn_pv2_kernel<<<NB * NH, 256, 0, stream>>>(qkv8, qkv8 + (size_t)NM * NDM, vi8, mb, scl,
                                               xout, sclu + 7);

  quant_a_kernel<<<dim3(512, 1), 256, 0, stream>>>(xout, xout, xout, xq, sclu, 7);
  gemm_kernel<false><<<dim3(NM / BM, NDM / BN, 1), 256, 0, stream>>>(
      xq, wob, colsum, bo, bo, bo, (float*)d_out, sclu, rmax_part);
}